// Round 5
// baseline (229.461 us; speedup 1.0000x reference)
//
#include <hip/hip_runtime.h>

#define T 200
#define E 64
#define TPAD 256
#define ROW 72
#define BDIM 256

typedef __bf16 bf16_t;
typedef __bf16 bf16x8 __attribute__((ext_vector_type(8)));
typedef float f32x4 __attribute__((ext_vector_type(4)));

// ---- pre-pass: emb fp32 -> bf16 into workspace (halves gather bytes) ----
__global__ __launch_bounds__(256) void emb_cvt(const float* __restrict__ src,
                                               bf16_t* __restrict__ dst, int n8) {
    const int i = blockIdx.x * 256 + threadIdx.x;
    if (i >= n8) return;
    const float4* s = (const float4*)src + (size_t)i * 2;
    const float4 a = s[0], b = s[1];
    union { bf16_t h[8]; uint4 v; } u;
    u.h[0] = (bf16_t)a.x; u.h[1] = (bf16_t)a.y; u.h[2] = (bf16_t)a.z; u.h[3] = (bf16_t)a.w;
    u.h[4] = (bf16_t)b.x; u.h[5] = (bf16_t)b.y; u.h[6] = (bf16_t)b.z; u.h[7] = (bf16_t)b.w;
    ((uint4*)dst)[i] = u.v;
}

// ---- pre-pass: fold w1 into batch-independent pieces (fp32, exact) ----
__global__ __launch_bounds__(256) void w1_cvt(const float* __restrict__ w1,
                                              float* __restrict__ Ap,
                                              float* __restrict__ Ctf,
                                              float* __restrict__ Dtf) {
    const int idx = blockIdx.x * 256 + threadIdx.x;   // 0..4095
    const int e = idx >> 6, j = idx & 63;
    const float a = w1[e * 64 + j];
    const float b = w1[(64 + e) * 64 + j];
    const float c = w1[(128 + e) * 64 + j];
    const float d = w1[(192 + e) * 64 + j];
    Ap[e * 64 + j]  = a + c;
    Ctf[j * 64 + e] = b - c;
    Dtf[j * 64 + e] = d;
}

// ====== fast kernel: 26944 B LDS (block 27136) -> 6 blocks/CU by LDS ======
// Key fix vs R4: M^T never touches LDS (bF built per-lane in registers from
// Ctf/Dtf/q), so kr stages to sK immediately after B0 -> kr and bF are never
// co-live -> no spill (R3/R4's 100+ MB scratch traffic).
// sK swizzle: byte(r, chunk c) = r*128 + ((c*16) ^ ((r&7)<<4))
__global__ __launch_bounds__(256, 4) void din_fast(
    const int* __restrict__ query,
    const int* __restrict__ keys,
    const bf16_t* __restrict__ emb16,
    const float* __restrict__ Ap,
    const float* __restrict__ Ctf,
    const float* __restrict__ Dtf,
    const float* __restrict__ b1,
    const float* __restrict__ w2,
    const float* __restrict__ b2,
    const float* __restrict__ dw1,
    const float* __restrict__ db1,
    const float* __restrict__ dw2,
    const float* __restrict__ db2,
    const float* __restrict__ ow,
    const float* __restrict__ ob,
    float* __restrict__ out)
{
    __shared__ __align__(16) char smem[26944];
    // sK    [0, 25600)      200x64 bf16, swizzled
    // sWgt  [25600, 26432)  208 f32 scores/weights (written post-B1 by MFMA)
    //   overlays: sQf = 25600 (64 f32, dead at B1; MFMA writes only after B1)
    //             sD1 = 25600 (post-interest), sD2 = 26112 (post-mlp1)
    // sUP   [26432, 26944)  128 f32 u-partials (read as uv right after B1)
    //   overlay: sIP = 26432 (interest partials, written post-B3)
    float* sWgt = (float*)(smem + 25600);
    float* sQf  = (float*)(smem + 25600);
    float* sD1  = (float*)(smem + 25600);
    float* sD2  = (float*)(smem + 26112);
    float* sUP  = (float*)(smem + 26432);
    float* sIP  = (float*)(smem + 26432);

    const int tid  = threadIdx.x;
    const int lane = tid & 63;
    const int wid  = tid >> 6;
    const int b    = blockIdx.x;
    const float b2v = b2[0];

    // ---- phase 0: issue long-latency gathers + query row ----
    uint4 kr[8];
    if (tid < T) {
        const int ki = keys[b * T + tid];
        const uint4* kp = (const uint4*)(emb16 + (size_t)ki * E);
        #pragma unroll
        for (int c = 0; c < 8; ++c) kr[c] = kp[c];
    }
    const int qi = query[b];
    if (tid < 64) sQf[tid] = (float)emb16[(size_t)qi * E + tid];
    __syncthreads();                                   // B0: sQf ready (gathers drained too)

    // ---- phase 1a: stage kr -> sK (swizzled) FIRST, so kr regs retire ----
    if (tid < T) {
        char* rowp = smem + tid * 128;
        const int rx = (tid & 7) << 4;
        #pragma unroll
        for (int c = 0; c < 8; ++c)
            *(uint4*)(rowp + ((c * 16) ^ rx)) = kr[c];
    }
    __builtin_amdgcn_sched_barrier(0);                 // keep kr/bF liveness disjoint

    // ---- phase 1b: u partials (tid<128): u[j] = sum_e q[e] * Ap[e][j] ----
    {
        const int j = tid & 63, h = tid >> 6;
        if (tid < 128) {
            float au = 0.f;
            #pragma unroll
            for (int eo = 0; eo < 32; ++eo) {
                const int e = h * 32 + eo;
                au = fmaf(sQf[e], Ap[e * 64 + j], au);
            }
            sUP[tid] = au;
        }
    }

    // ---- phase 1c: build B-fragments (M^T) directly in registers ----
    const int n    = lane & 15;
    const int quad = lane >> 4;
    float w2v[4];
    bf16x8 bF[4][2];
    #pragma unroll
    for (int nt = 0; nt < 4; ++nt) {
        const int jj = nt * 16 + n;
        w2v[nt] = w2[jj];
        const float* cb = Ctf + jj * 64;
        const float* db = Dtf + jj * 64;
        const float4 ca0 = *(const float4*)(cb + quad * 8);
        const float4 ca1 = *(const float4*)(cb + quad * 8 + 4);
        const float4 da0 = *(const float4*)(db + quad * 8);
        const float4 da1 = *(const float4*)(db + quad * 8 + 4);
        const float4 cb0 = *(const float4*)(cb + 32 + quad * 8);
        const float4 cb1 = *(const float4*)(cb + 32 + quad * 8 + 4);
        const float4 db0 = *(const float4*)(db + 32 + quad * 8);
        const float4 db1 = *(const float4*)(db + 32 + quad * 8 + 4);
        const float* q0 = sQf + quad * 8;
        const float* q1 = sQf + 32 + quad * 8;
        union { bf16_t h[8]; bf16x8 v; } u0, u1;
        u0.h[0] = (bf16_t)fmaf(q0[0], da0.x, ca0.x);
        u0.h[1] = (bf16_t)fmaf(q0[1], da0.y, ca0.y);
        u0.h[2] = (bf16_t)fmaf(q0[2], da0.z, ca0.z);
        u0.h[3] = (bf16_t)fmaf(q0[3], da0.w, ca0.w);
        u0.h[4] = (bf16_t)fmaf(q0[4], da1.x, ca1.x);
        u0.h[5] = (bf16_t)fmaf(q0[5], da1.y, ca1.y);
        u0.h[6] = (bf16_t)fmaf(q0[6], da1.z, ca1.z);
        u0.h[7] = (bf16_t)fmaf(q0[7], da1.w, ca1.w);
        u1.h[0] = (bf16_t)fmaf(q1[0], db0.x, cb0.x);
        u1.h[1] = (bf16_t)fmaf(q1[1], db0.y, cb0.y);
        u1.h[2] = (bf16_t)fmaf(q1[2], db0.z, cb0.z);
        u1.h[3] = (bf16_t)fmaf(q1[3], db0.w, cb0.w);
        u1.h[4] = (bf16_t)fmaf(q1[4], db1.x, cb1.x);
        u1.h[5] = (bf16_t)fmaf(q1[5], db1.y, cb1.y);
        u1.h[6] = (bf16_t)fmaf(q1[6], db1.z, cb1.z);
        u1.h[7] = (bf16_t)fmaf(q1[7], db1.w, cb1.w);
        bF[nt][0] = u0.v;
        bF[nt][1] = u1.v;
    }
    __syncthreads();                                   // B1: sK, sUP ready; sQf dead

    // ---- phase 2: MFMA score GEMM: h_pre = u + k(208x64) * M(64x64) ----
    // tile 12 rows 200..207 read scratch garbage (in-bounds) -> masked in softmax
    {
        float uv[4];
        #pragma unroll
        for (int nt = 0; nt < 4; ++nt) {
            const int jj = nt * 16 + n;
            uv[nt] = b1[jj] + sUP[jj] + sUP[64 + jj];
        }
        const int rxn = (n & 7) << 4;
        for (int mt = wid; mt < 13; mt += 4) {
            const char* rp = smem + (mt * 16 + n) * 128;
            const bf16x8 a0 = *(const bf16x8*)(rp + ((quad * 16) ^ rxn));
            const bf16x8 a1 = *(const bf16x8*)(rp + ((64 + quad * 16) ^ rxn));
            float s0 = 0.f, s1 = 0.f, s2 = 0.f, s3 = 0.f;
            #pragma unroll
            for (int nt = 0; nt < 4; ++nt) {
                f32x4 acc = { uv[nt], uv[nt], uv[nt], uv[nt] };
                acc = __builtin_amdgcn_mfma_f32_16x16x32_bf16(a0, bF[nt][0], acc, 0, 0, 0);
                acc = __builtin_amdgcn_mfma_f32_16x16x32_bf16(a1, bF[nt][1], acc, 0, 0, 0);
                s0 = fmaf(fmaxf(acc[0], 0.f), w2v[nt], s0);
                s1 = fmaf(fmaxf(acc[1], 0.f), w2v[nt], s1);
                s2 = fmaf(fmaxf(acc[2], 0.f), w2v[nt], s2);
                s3 = fmaf(fmaxf(acc[3], 0.f), w2v[nt], s3);
            }
            #pragma unroll
            for (int off = 1; off < 16; off <<= 1) {
                s0 += __shfl_xor(s0, off);
                s1 += __shfl_xor(s1, off);
                s2 += __shfl_xor(s2, off);
                s3 += __shfl_xor(s3, off);
            }
            if (n == 0) {
                const int base = mt * 16 + quad * 4;
                sWgt[base + 0] = s0;
                sWgt[base + 1] = s1;
                sWgt[base + 2] = s2;
                sWgt[base + 3] = s3;
            }
        }
    }
    __syncthreads();                                   // B2: scores ready

    // ---- phase 3: single-wave softmax, normalization folded in ----
    if (wid == 0) {
        const float x0 = sWgt[lane] + b2v;
        const float x1 = sWgt[64 + lane] + b2v;
        const float x2 = sWgt[128 + lane] + b2v;
        const float x3 = (lane < 8) ? (sWgt[192 + lane] + b2v) : -1e30f;
        float m = fmaxf(fmaxf(x0, x1), fmaxf(x2, x3));
        #pragma unroll
        for (int off = 32; off > 0; off >>= 1) m = fmaxf(m, __shfl_xor(m, off));
        const float p0 = __expf(x0 - m);
        const float p1 = __expf(x1 - m);
        const float p2 = __expf(x2 - m);
        const float p3 = (lane < 8) ? __expf(x3 - m) : 0.f;
        float s = ((p0 + p1) + (p2 + p3));
        #pragma unroll
        for (int off = 32; off > 0; off >>= 1) s += __shfl_xor(s, off);
        const float inv = 1.f / s;
        sWgt[lane]       = p0 * inv;
        sWgt[64 + lane]  = p1 * inv;
        sWgt[128 + lane] = p2 * inv;
        if (lane < 8) sWgt[192 + lane] = p3 * inv;
    }
    __syncthreads();                                   // B3: weights ready

    // ---- phase 4: interest partials (tid<128, 2-way t-split, 4 acc chains) ----
    if (tid < 128) {
        const int e2 = (tid & 63) * 2;                 // byte offset of e
        const int bt = (tid >> 6) * 100;
        float a0 = 0.f, a1 = 0.f, a2 = 0.f, a3 = 0.f;
        #pragma unroll 5
        for (int tt = 0; tt < 100; tt += 4) {
            const int t0 = bt + tt;
            const float k0 = (float)*(const bf16_t*)(smem + (t0    ) * 128 + (e2 ^ (((t0    ) & 7) << 4)));
            const float k1 = (float)*(const bf16_t*)(smem + (t0 + 1) * 128 + (e2 ^ (((t0 + 1) & 7) << 4)));
            const float k2 = (float)*(const bf16_t*)(smem + (t0 + 2) * 128 + (e2 ^ (((t0 + 2) & 7) << 4)));
            const float k3 = (float)*(const bf16_t*)(smem + (t0 + 3) * 128 + (e2 ^ (((t0 + 3) & 7) << 4)));
            a0 = fmaf(sWgt[t0], k0, a0);
            a1 = fmaf(sWgt[t0 + 1], k1, a1);
            a2 = fmaf(sWgt[t0 + 2], k2, a2);
            a3 = fmaf(sWgt[t0 + 3], k3, a3);
        }
        sIP[tid] = (a0 + a1) + (a2 + a3);
    }
    __syncthreads();                                   // B4: sIP ready; sWgt dead

    // ---- phase 5: deep MLP 64 -> 128 (sD1 overlays sWgt) ----
    if (tid < 128) {
        float a = db1[tid];
        #pragma unroll 8
        for (int e = 0; e < 64; ++e)
            a = fmaf(sIP[e] + sIP[64 + e], dw1[e * 128 + tid], a);
        sD1[tid] = fmaxf(a, 0.f);
    }
    __syncthreads();                                   // B5
    // ---- phase 6: 128 -> 64 ----
    if (tid < 64) {
        float a = db2[tid];
        #pragma unroll 8
        for (int i = 0; i < 128; ++i) a = fmaf(sD1[i], dw2[i * 64 + tid], a);
        sD2[tid] = fmaxf(a, 0.f);
    }
    __syncthreads();                                   // B6
    // ---- phase 7: output ----
    if (tid < 64) {
        float v = sD2[tid] * ow[tid];
        #pragma unroll
        for (int off = 32; off > 0; off >>= 1) v += __shfl_xor(v, off);
        if (tid == 0) out[b] = 1.f / (1.f + __expf(-(v + ob[0])));
    }
}

// ============ fallback: previous verified kernel (ws too small) ============
__global__ __launch_bounds__(BDIM, 3) void din_kernel(
    const int* __restrict__ query,
    const int* __restrict__ keys,
    const float* __restrict__ embf,
    const bf16_t* __restrict__ emb16,
    const int use16,
    const float* __restrict__ w1,
    const float* __restrict__ b1,
    const float* __restrict__ w2,
    const float* __restrict__ b2,
    const float* __restrict__ dw1,
    const float* __restrict__ db1,
    const float* __restrict__ dw2,
    const float* __restrict__ db2,
    const float* __restrict__ ow,
    const float* __restrict__ ob,
    float* __restrict__ out)
{
    __shared__ __align__(16) char sRaw[TPAD * ROW * 2];
    __shared__ __align__(16) bf16_t sMt[64 * ROW];
    __shared__ float sU[64];
    __shared__ float sUP[256];
    __shared__ float sW2f[64];
    __shared__ float sWgt[256];
    __shared__ float sQf[64];
    __shared__ __align__(16) char sQtmp[128];
    __shared__ float sRed[8];
    __shared__ float sInt[64];
    __shared__ float sD1[128];
    __shared__ float sD2[64];

    const int tid  = threadIdx.x;
    const int lane = tid & 63;
    const int wid  = tid >> 6;
    const int b    = blockIdx.x;
    const float b2v = b2[0];

    uint4 kr[8];
    if (tid < T) {
        const int ki = keys[b * T + tid];
        if (use16) {
            const uint4* kp = (const uint4*)(emb16 + (size_t)ki * E);
            #pragma unroll
            for (int c = 0; c < 8; ++c) kr[c] = kp[c];
        } else {
            const float4* kp = (const float4*)(embf + (size_t)ki * E);
            #pragma unroll
            for (int c = 0; c < 8; ++c) {
                const float4 x = kp[2 * c], y = kp[2 * c + 1];
                union { bf16_t h[8]; uint4 v; } u;
                u.h[0] = (bf16_t)x.x; u.h[1] = (bf16_t)x.y; u.h[2] = (bf16_t)x.z; u.h[3] = (bf16_t)x.w;
                u.h[4] = (bf16_t)y.x; u.h[5] = (bf16_t)y.y; u.h[6] = (bf16_t)y.z; u.h[7] = (bf16_t)y.w;
                kr[c] = u.v;
            }
        }
    } else {
        #pragma unroll
        for (int c = 0; c < 8; ++c) kr[c] = make_uint4(0u, 0u, 0u, 0u);
    }

    const int qi = query[b];
    if (tid < 8) {
        uint4 qv;
        if (use16) {
            qv = ((const uint4*)(emb16 + (size_t)qi * E))[tid];
        } else {
            const float4 x = ((const float4*)(embf + (size_t)qi * E))[2 * tid];
            const float4 y = ((const float4*)(embf + (size_t)qi * E))[2 * tid + 1];
            union { bf16_t h[8]; uint4 v; } u;
            u.h[0] = (bf16_t)x.x; u.h[1] = (bf16_t)x.y; u.h[2] = (bf16_t)x.z; u.h[3] = (bf16_t)x.w;
            u.h[4] = (bf16_t)y.x; u.h[5] = (bf16_t)y.y; u.h[6] = (bf16_t)y.z; u.h[7] = (bf16_t)y.w;
            qv = u.v;
        }
        ((uint4*)sQtmp)[tid] = qv;
    }
    if (tid < 64) sW2f[tid] = w2[tid];
    __syncthreads();
    if (tid < 64) sQf[tid] = (float)((const bf16_t*)sQtmp)[tid];
    __syncthreads();

    {
        float* sTmp = (float*)sRaw;
        const int j = tid & 63, ec = tid >> 6;
        float au = 0.f;
        #pragma unroll
        for (int eo = 0; eo < 16; ++eo) {
            const int e = ec * 16 + eo;
            const float w1a = w1[e * 64 + j];
            const float w1b = w1[(64 + e) * 64 + j];
            const float w1c = w1[(128 + e) * 64 + j];
            const float w1d = w1[(192 + e) * 64 + j];
            sTmp[e * 65 + j] = w1b - w1c + sQf[e] * w1d;
            au = fmaf(sQf[e], w1a + w1c, au);
        }
        sUP[tid] = au;
    }
    __syncthreads();
    {
        const float* sTmp = (const float*)sRaw;
        const int e = tid & 63, jc = tid >> 6;
        #pragma unroll
        for (int jo = 0; jo < 16; ++jo) {
            const int j = jc * 16 + jo;
            sMt[j * ROW + e] = (bf16_t)sTmp[e * 65 + j];
        }
    }
    if (tid < 64) sU[tid] = b1[tid] + sUP[tid] + sUP[64 + tid] + sUP[128 + tid] + sUP[192 + tid];
    __syncthreads();

    bf16_t* sK = (bf16_t*)sRaw;
    {
        uint4* dst = (uint4*)(sK + tid * ROW);
        #pragma unroll
        for (int c = 0; c < 8; ++c) dst[c] = kr[c];
    }
    __syncthreads();

    {
        const int n    = lane & 15;
        const int quad = lane >> 4;
        float w2v[4], uv[4];
        bf16x8 bF[4][2];
        #pragma unroll
        for (int nt = 0; nt < 4; ++nt) {
            w2v[nt] = sW2f[nt * 16 + n];
            uv[nt]  = sU[nt * 16 + n];
            bF[nt][0] = *(const bf16x8*)&sMt[(nt * 16 + n) * ROW + quad * 8];
            bF[nt][1] = *(const bf16x8*)&sMt[(nt * 16 + n) * ROW + 32 + quad * 8];
        }
        #pragma unroll
        for (int i = 0; i < 4; ++i) {
            const int mt = wid * 4 + i;
            const bf16x8 a0 = *(const bf16x8*)&sK[(mt * 16 + n) * ROW + quad * 8];
            const bf16x8 a1 = *(const bf16x8*)&sK[(mt * 16 + n) * ROW + 32 + quad * 8];
            float s0 = 0.f, s1 = 0.f, s2 = 0.f, s3 = 0.f;
            #pragma unroll
            for (int nt = 0; nt < 4; ++nt) {
                f32x4 acc = { uv[nt], uv[nt], uv[nt], uv[nt] };
                acc = __builtin_amdgcn_mfma_f32_16x16x32_bf16(a0, bF[nt][0], acc, 0, 0, 0);
                acc = __builtin_amdgcn_mfma_f32_16x16x32_bf16(a1, bF[nt][1], acc, 0, 0, 0);
                s0 = fmaf(fmaxf(acc[0], 0.f), w2v[nt], s0);
                s1 = fmaf(fmaxf(acc[1], 0.f), w2v[nt], s1);
                s2 = fmaf(fmaxf(acc[2], 0.f), w2v[nt], s2);
                s3 = fmaf(fmaxf(acc[3], 0.f), w2v[nt], s3);
            }
            #pragma unroll
            for (int off = 1; off < 16; off <<= 1) {
                s0 += __shfl_xor(s0, off);
                s1 += __shfl_xor(s1, off);
                s2 += __shfl_xor(s2, off);
                s3 += __shfl_xor(s3, off);
            }
            if (n == 0) {
                const int base = mt * 16 + quad * 4;
                sWgt[base + 0] = s0;
                sWgt[base + 1] = s1;
                sWgt[base + 2] = s2;
                sWgt[base + 3] = s3;
            }
        }
    }
    __syncthreads();

    {
        const float score = (tid < T) ? (sWgt[tid] + b2v) : -1e30f;
        float m = score;
        #pragma unroll
        for (int off = 32; off > 0; off >>= 1) m = fmaxf(m, __shfl_xor(m, off));
        if (lane == 0) sRed[wid] = m;
        __syncthreads();
        const float gmax = fmaxf(fmaxf(sRed[0], sRed[1]), fmaxf(sRed[2], sRed[3]));
        const float p = (tid < T) ? __expf(score - gmax) : 0.f;
        float s = p;
        #pragma unroll
        for (int off = 32; off > 0; off >>= 1) s += __shfl_xor(s, off);
        if (lane == 0) sRed[4 + wid] = s;
        __syncthreads();
        const float gsum = sRed[4] + sRed[5] + sRed[6] + sRed[7];
        sWgt[tid] = p / gsum;
    }
    __syncthreads();

    {
        const int e = tid & 63, ch = tid >> 6;
        float a = 0.f;
        #pragma unroll 8
        for (int tt = 0; tt < 64; ++tt) {
            const int t = ch * 64 + tt;
            a = fmaf(sWgt[t], (float)sK[t * ROW + e], a);
        }
        sUP[tid] = a;
    }
    __syncthreads();
    if (tid < 64) sInt[tid] = sUP[tid] + sUP[64 + tid] + sUP[128 + tid] + sUP[192 + tid];
    __syncthreads();

    if (tid < 128) {
        float a = db1[tid];
        #pragma unroll 8
        for (int e = 0; e < 64; ++e) a = fmaf(sInt[e], dw1[e * 128 + tid], a);
        sD1[tid] = fmaxf(a, 0.f);
    }
    __syncthreads();
    if (tid < 64) {
        float a = db2[tid];
        #pragma unroll 8
        for (int i = 0; i < 128; ++i) a = fmaf(sD1[i], dw2[i * 64 + tid], a);
        sD2[tid] = fmaxf(a, 0.f);
    }
    __syncthreads();
    if (tid < 64) {
        float v = sD2[tid] * ow[tid];
        #pragma unroll
        for (int off = 32; off > 0; off >>= 1) v += __shfl_xor(v, off);
        if (tid == 0) out[b] = 1.f / (1.f + __expf(-(v + ob[0])));
    }
}

extern "C" void kernel_launch(void* const* d_in, const int* in_sizes, int n_in,
                              void* d_out, int out_size, void* d_ws, size_t ws_size,
                              hipStream_t stream) {
    const int*   query = (const int*)d_in[0];
    const int*   keys  = (const int*)d_in[1];
    const float* embf  = (const float*)d_in[2];
    const float* w1    = (const float*)d_in[3];
    const float* b1    = (const float*)d_in[4];
    const float* w2    = (const float*)d_in[5];
    const float* b2    = (const float*)d_in[6];
    const float* dw1   = (const float*)d_in[7];
    const float* db1   = (const float*)d_in[8];
    const float* dw2   = (const float*)d_in[9];
    const float* db2   = (const float*)d_in[10];
    const float* ow    = (const float*)d_in[11];
    const float* ob    = (const float*)d_in[12];
    float* out = (float*)d_out;
    const int B        = in_sizes[0];
    const int embElems = in_sizes[2];                  // VOCAB * E
    const size_t WOFF  = 49152;                        // Ap 16K | Ctf 16K | Dtf 16K

    if (ws_size >= WOFF + (size_t)embElems * 2) {
        float*  Ap    = (float*)d_ws;
        float*  Ctf   = (float*)((char*)d_ws + 16384);
        float*  Dtf   = (float*)((char*)d_ws + 32768);
        bf16_t* emb16 = (bf16_t*)((char*)d_ws + WOFF);
        const int n8 = embElems / 8;
        w1_cvt<<<16, 256, 0, stream>>>(w1, Ap, Ctf, Dtf);
        emb_cvt<<<(n8 + 255) / 256, 256, 0, stream>>>(embf, emb16, n8);
        din_fast<<<B, BDIM, 0, stream>>>(query, keys, emb16, Ap, Ctf, Dtf,
                                         b1, w2, b2, dw1, db1, dw2, db2, ow, ob, out);
    } else {
        const int use16 = (ws_size >= (size_t)embElems * 2) ? 1 : 0;
        bf16_t* emb16 = (bf16_t*)d_ws;
        if (use16) {
            const int n8 = embElems / 8;
            emb_cvt<<<(n8 + 255) / 256, 256, 0, stream>>>(embf, emb16, n8);
        }
        din_kernel<<<B, BDIM, 0, stream>>>(query, keys, embf, emb16, use16,
                                           w1, b1, w2, b2, dw1, db1, dw2, db2, ow, ob, out);
    }
}

// Round 6
// 206.959 us; speedup vs baseline: 1.1087x; 1.1087x over previous
//
#include <hip/hip_runtime.h>

#define T 200
#define E 64
#define TPAD 256
#define ROW 72
#define BDIM 256

typedef __bf16 bf16_t;
typedef __bf16 bf16x8 __attribute__((ext_vector_type(8)));
typedef float f32x4 __attribute__((ext_vector_type(4)));

// ---- pre-pass: emb fp32 -> bf16 into workspace (halves gather bytes) ----
__global__ __launch_bounds__(256) void emb_cvt(const float* __restrict__ src,
                                               bf16_t* __restrict__ dst, int n8) {
    const int i = blockIdx.x * 256 + threadIdx.x;
    if (i >= n8) return;
    const float4* s = (const float4*)src + (size_t)i * 2;
    const float4 a = s[0], b = s[1];
    union { bf16_t h[8]; uint4 v; } u;
    u.h[0] = (bf16_t)a.x; u.h[1] = (bf16_t)a.y; u.h[2] = (bf16_t)a.z; u.h[3] = (bf16_t)a.w;
    u.h[4] = (bf16_t)b.x; u.h[5] = (bf16_t)b.y; u.h[6] = (bf16_t)b.z; u.h[7] = (bf16_t)b.w;
    ((uint4*)dst)[i] = u.v;
}

// ---- pre-pass: fold w1 into batch-independent pieces (fp32, exact) ----
__global__ __launch_bounds__(256) void w1_cvt(const float* __restrict__ w1,
                                              float* __restrict__ Ap,
                                              float* __restrict__ Ctf,
                                              float* __restrict__ Dtf) {
    const int idx = blockIdx.x * 256 + threadIdx.x;   // 0..4095
    const int e = idx >> 6, j = idx & 63;
    const float a = w1[e * 64 + j];
    const float b = w1[(64 + e) * 64 + j];
    const float c = w1[(128 + e) * 64 + j];
    const float d = w1[(192 + e) * 64 + j];
    Ap[e * 64 + j]  = a + c;
    Ctf[j * 64 + e] = b - c;
    Dtf[j * 64 + e] = d;
}

// ====== fast kernel: 26944 B LDS (block 27136) -> 6 blocks/CU by LDS ======
// R6 anti-spill fixes vs R5 (kr was demoted to scratch -> 102 MB HBM writes):
//  (1) kr fully defined on ALL threads (else zero-fill) — conditionally-defined
//      values crossing divergent joins + barrier defeat register promotion.
//  (2) MFMA m-loop fully unrolled (3 tiles/wave + wave0 tail) — no runtime loop.
// sK swizzle: byte(r, chunk c) = r*128 + ((c*16) ^ ((r&7)<<4)); 0 bank conflicts (R5).
__global__ __launch_bounds__(256, 4) void din_fast(
    const int* __restrict__ query,
    const int* __restrict__ keys,
    const bf16_t* __restrict__ emb16,
    const float* __restrict__ Ap,
    const float* __restrict__ Ctf,
    const float* __restrict__ Dtf,
    const float* __restrict__ b1,
    const float* __restrict__ w2,
    const float* __restrict__ b2,
    const float* __restrict__ dw1,
    const float* __restrict__ db1,
    const float* __restrict__ dw2,
    const float* __restrict__ db2,
    const float* __restrict__ ow,
    const float* __restrict__ ob,
    float* __restrict__ out)
{
    __shared__ __align__(16) char smem[26944];
    // sK    [0, 25600)      200x64 bf16, swizzled
    // sWgt  [25600, 26432)  208 f32 scores/weights (written post-B1 by MFMA)
    //   overlays: sQf = 25600 (64 f32, dead at B1)
    //             sD1 = 25600 (post-interest), sD2 = 26112 (post-mlp1)
    // sUP   [26432, 26944)  128 f32 u-partials (read as uv right after B1)
    //   overlay: sIP = 26432 (interest partials, written post-B3)
    float* sWgt = (float*)(smem + 25600);
    float* sQf  = (float*)(smem + 25600);
    float* sD1  = (float*)(smem + 25600);
    float* sD2  = (float*)(smem + 26112);
    float* sUP  = (float*)(smem + 26432);
    float* sIP  = (float*)(smem + 26432);

    const int tid  = threadIdx.x;
    const int lane = tid & 63;
    const int wid  = tid >> 6;
    const int b    = blockIdx.x;
    const float b2v = b2[0];

    // ---- phase 0: issue long-latency gathers + query row ----
    uint4 kr[8];
    if (tid < T) {
        const int ki = keys[b * T + tid];
        const uint4* kp = (const uint4*)(emb16 + (size_t)ki * E);
        #pragma unroll
        for (int c = 0; c < 8; ++c) kr[c] = kp[c];
    } else {
        #pragma unroll
        for (int c = 0; c < 8; ++c) kr[c] = make_uint4(0u, 0u, 0u, 0u);
    }
    const int qi = query[b];
    if (tid < 64) sQf[tid] = (float)emb16[(size_t)qi * E + tid];
    __syncthreads();                                   // B0: sQf ready

    // ---- phase 1a: stage kr -> sK (swizzled) FIRST, so kr regs retire ----
    if (tid < T) {
        char* rowp = smem + tid * 128;
        const int rx = (tid & 7) << 4;
        #pragma unroll
        for (int c = 0; c < 8; ++c)
            *(uint4*)(rowp + ((c * 16) ^ rx)) = kr[c];
    }
    __builtin_amdgcn_sched_barrier(0);                 // keep kr/bF liveness disjoint

    // ---- phase 1b: u partials (tid<128): u[j] = sum_e q[e] * Ap[e][j] ----
    {
        const int j = tid & 63, h = tid >> 6;
        if (tid < 128) {
            float au = 0.f;
            #pragma unroll
            for (int eo = 0; eo < 32; ++eo) {
                const int e = h * 32 + eo;
                au = fmaf(sQf[e], Ap[e * 64 + j], au);
            }
            sUP[tid] = au;
        }
    }

    // ---- phase 1c: build B-fragments (M^T) directly in registers ----
    const int n    = lane & 15;
    const int quad = lane >> 4;
    float w2v[4];
    bf16x8 bF[4][2];
    #pragma unroll
    for (int nt = 0; nt < 4; ++nt) {
        const int jj = nt * 16 + n;
        w2v[nt] = w2[jj];
        const float* cb = Ctf + jj * 64;
        const float* db = Dtf + jj * 64;
        const float* q0 = sQf + quad * 8;
        const float* q1 = sQf + 32 + quad * 8;
        union { bf16_t h[8]; bf16x8 v; } u0, u1;
        {
            const float4 ca0 = *(const float4*)(cb + quad * 8);
            const float4 ca1 = *(const float4*)(cb + quad * 8 + 4);
            const float4 da0 = *(const float4*)(db + quad * 8);
            const float4 da1 = *(const float4*)(db + quad * 8 + 4);
            u0.h[0] = (bf16_t)fmaf(q0[0], da0.x, ca0.x);
            u0.h[1] = (bf16_t)fmaf(q0[1], da0.y, ca0.y);
            u0.h[2] = (bf16_t)fmaf(q0[2], da0.z, ca0.z);
            u0.h[3] = (bf16_t)fmaf(q0[3], da0.w, ca0.w);
            u0.h[4] = (bf16_t)fmaf(q0[4], da1.x, ca1.x);
            u0.h[5] = (bf16_t)fmaf(q0[5], da1.y, ca1.y);
            u0.h[6] = (bf16_t)fmaf(q0[6], da1.z, ca1.z);
            u0.h[7] = (bf16_t)fmaf(q0[7], da1.w, ca1.w);
        }
        {
            const float4 cb0 = *(const float4*)(cb + 32 + quad * 8);
            const float4 cb1 = *(const float4*)(cb + 32 + quad * 8 + 4);
            const float4 db0 = *(const float4*)(db + 32 + quad * 8);
            const float4 db1 = *(const float4*)(db + 32 + quad * 8 + 4);
            u1.h[0] = (bf16_t)fmaf(q1[0], db0.x, cb0.x);
            u1.h[1] = (bf16_t)fmaf(q1[1], db0.y, cb0.y);
            u1.h[2] = (bf16_t)fmaf(q1[2], db0.z, cb0.z);
            u1.h[3] = (bf16_t)fmaf(q1[3], db0.w, cb0.w);
            u1.h[4] = (bf16_t)fmaf(q1[4], db1.x, cb1.x);
            u1.h[5] = (bf16_t)fmaf(q1[5], db1.y, cb1.y);
            u1.h[6] = (bf16_t)fmaf(q1[6], db1.z, cb1.z);
            u1.h[7] = (bf16_t)fmaf(q1[7], db1.w, cb1.w);
        }
        bF[nt][0] = u0.v;
        bF[nt][1] = u1.v;
    }
    __syncthreads();                                   // B1: sK, sUP ready; sQf dead

    // ---- phase 2: MFMA score GEMM: h_pre = u + k(208x64) * M(64x64) ----
    // tiles: wave w does {w, w+4, w+8}; wave 0 also tile 12 (rows 200..207 are
    // in-bounds LDS garbage, masked in softmax). Fully compile-time unrolled.
    {
        float uv[4];
        #pragma unroll
        for (int nt = 0; nt < 4; ++nt) {
            const int jj = nt * 16 + n;
            uv[nt] = b1[jj] + sUP[jj] + sUP[64 + jj];
        }
        const int rxn = (n & 7) << 4;
        auto score_tile = [&](int mt) {
            const char* rp = smem + (mt * 16 + n) * 128;
            const bf16x8 a0 = *(const bf16x8*)(rp + ((quad * 16) ^ rxn));
            const bf16x8 a1 = *(const bf16x8*)(rp + ((64 + quad * 16) ^ rxn));
            float s0 = 0.f, s1 = 0.f, s2 = 0.f, s3 = 0.f;
            #pragma unroll
            for (int nt = 0; nt < 4; ++nt) {
                f32x4 acc = { uv[nt], uv[nt], uv[nt], uv[nt] };
                acc = __builtin_amdgcn_mfma_f32_16x16x32_bf16(a0, bF[nt][0], acc, 0, 0, 0);
                acc = __builtin_amdgcn_mfma_f32_16x16x32_bf16(a1, bF[nt][1], acc, 0, 0, 0);
                s0 = fmaf(fmaxf(acc[0], 0.f), w2v[nt], s0);
                s1 = fmaf(fmaxf(acc[1], 0.f), w2v[nt], s1);
                s2 = fmaf(fmaxf(acc[2], 0.f), w2v[nt], s2);
                s3 = fmaf(fmaxf(acc[3], 0.f), w2v[nt], s3);
            }
            #pragma unroll
            for (int off = 1; off < 16; off <<= 1) {
                s0 += __shfl_xor(s0, off);
                s1 += __shfl_xor(s1, off);
                s2 += __shfl_xor(s2, off);
                s3 += __shfl_xor(s3, off);
            }
            if (n == 0) {
                const int base = mt * 16 + quad * 4;
                sWgt[base + 0] = s0;
                sWgt[base + 1] = s1;
                sWgt[base + 2] = s2;
                sWgt[base + 3] = s3;
            }
        };
        #pragma unroll
        for (int i = 0; i < 3; ++i) score_tile(wid + 4 * i);
        if (wid == 0) score_tile(12);
    }
    __syncthreads();                                   // B2: scores ready

    // ---- phase 3: single-wave softmax, normalization folded in ----
    if (wid == 0) {
        const float x0 = sWgt[lane] + b2v;
        const float x1 = sWgt[64 + lane] + b2v;
        const float x2 = sWgt[128 + lane] + b2v;
        const float x3 = (lane < 8) ? (sWgt[192 + lane] + b2v) : -1e30f;
        float m = fmaxf(fmaxf(x0, x1), fmaxf(x2, x3));
        #pragma unroll
        for (int off = 32; off > 0; off >>= 1) m = fmaxf(m, __shfl_xor(m, off));
        const float p0 = __expf(x0 - m);
        const float p1 = __expf(x1 - m);
        const float p2 = __expf(x2 - m);
        const float p3 = (lane < 8) ? __expf(x3 - m) : 0.f;
        float s = ((p0 + p1) + (p2 + p3));
        #pragma unroll
        for (int off = 32; off > 0; off >>= 1) s += __shfl_xor(s, off);
        const float inv = 1.f / s;
        sWgt[lane]       = p0 * inv;
        sWgt[64 + lane]  = p1 * inv;
        sWgt[128 + lane] = p2 * inv;
        if (lane < 8) sWgt[192 + lane] = p3 * inv;
    }
    __syncthreads();                                   // B3: weights ready

    // ---- phase 4: interest partials (tid<128, 2-way t-split, 4 acc chains) ----
    if (tid < 128) {
        const int e2 = (tid & 63) * 2;                 // byte offset of e
        const int bt = (tid >> 6) * 100;
        float a0 = 0.f, a1 = 0.f, a2 = 0.f, a3 = 0.f;
        #pragma unroll 5
        for (int tt = 0; tt < 100; tt += 4) {
            const int t0 = bt + tt;
            const float k0 = (float)*(const bf16_t*)(smem + (t0    ) * 128 + (e2 ^ (((t0    ) & 7) << 4)));
            const float k1 = (float)*(const bf16_t*)(smem + (t0 + 1) * 128 + (e2 ^ (((t0 + 1) & 7) << 4)));
            const float k2 = (float)*(const bf16_t*)(smem + (t0 + 2) * 128 + (e2 ^ (((t0 + 2) & 7) << 4)));
            const float k3 = (float)*(const bf16_t*)(smem + (t0 + 3) * 128 + (e2 ^ (((t0 + 3) & 7) << 4)));
            a0 = fmaf(sWgt[t0], k0, a0);
            a1 = fmaf(sWgt[t0 + 1], k1, a1);
            a2 = fmaf(sWgt[t0 + 2], k2, a2);
            a3 = fmaf(sWgt[t0 + 3], k3, a3);
        }
        sIP[tid] = (a0 + a1) + (a2 + a3);
    }
    __syncthreads();                                   // B4: sIP ready; sWgt dead

    // ---- phase 5: deep MLP 64 -> 128 (sD1 overlays sWgt) ----
    if (tid < 128) {
        float a = db1[tid];
        #pragma unroll 8
        for (int e = 0; e < 64; ++e)
            a = fmaf(sIP[e] + sIP[64 + e], dw1[e * 128 + tid], a);
        sD1[tid] = fmaxf(a, 0.f);
    }
    __syncthreads();                                   // B5
    // ---- phase 6: 128 -> 64 ----
    if (tid < 64) {
        float a = db2[tid];
        #pragma unroll 8
        for (int i = 0; i < 128; ++i) a = fmaf(sD1[i], dw2[i * 64 + tid], a);
        sD2[tid] = fmaxf(a, 0.f);
    }
    __syncthreads();                                   // B6
    // ---- phase 7: output ----
    if (tid < 64) {
        float v = sD2[tid] * ow[tid];
        #pragma unroll
        for (int off = 32; off > 0; off >>= 1) v += __shfl_xor(v, off);
        if (tid == 0) out[b] = 1.f / (1.f + __expf(-(v + ob[0])));
    }
}

// ============ fallback: previous verified kernel (ws too small) ============
__global__ __launch_bounds__(BDIM, 3) void din_kernel(
    const int* __restrict__ query,
    const int* __restrict__ keys,
    const float* __restrict__ embf,
    const bf16_t* __restrict__ emb16,
    const int use16,
    const float* __restrict__ w1,
    const float* __restrict__ b1,
    const float* __restrict__ w2,
    const float* __restrict__ b2,
    const float* __restrict__ dw1,
    const float* __restrict__ db1,
    const float* __restrict__ dw2,
    const float* __restrict__ db2,
    const float* __restrict__ ow,
    const float* __restrict__ ob,
    float* __restrict__ out)
{
    __shared__ __align__(16) char sRaw[TPAD * ROW * 2];
    __shared__ __align__(16) bf16_t sMt[64 * ROW];
    __shared__ float sU[64];
    __shared__ float sUP[256];
    __shared__ float sW2f[64];
    __shared__ float sWgt[256];
    __shared__ float sQf[64];
    __shared__ __align__(16) char sQtmp[128];
    __shared__ float sRed[8];
    __shared__ float sInt[64];
    __shared__ float sD1[128];
    __shared__ float sD2[64];

    const int tid  = threadIdx.x;
    const int lane = tid & 63;
    const int wid  = tid >> 6;
    const int b    = blockIdx.x;
    const float b2v = b2[0];

    uint4 kr[8];
    if (tid < T) {
        const int ki = keys[b * T + tid];
        if (use16) {
            const uint4* kp = (const uint4*)(emb16 + (size_t)ki * E);
            #pragma unroll
            for (int c = 0; c < 8; ++c) kr[c] = kp[c];
        } else {
            const float4* kp = (const float4*)(embf + (size_t)ki * E);
            #pragma unroll
            for (int c = 0; c < 8; ++c) {
                const float4 x = kp[2 * c], y = kp[2 * c + 1];
                union { bf16_t h[8]; uint4 v; } u;
                u.h[0] = (bf16_t)x.x; u.h[1] = (bf16_t)x.y; u.h[2] = (bf16_t)x.z; u.h[3] = (bf16_t)x.w;
                u.h[4] = (bf16_t)y.x; u.h[5] = (bf16_t)y.y; u.h[6] = (bf16_t)y.z; u.h[7] = (bf16_t)y.w;
                kr[c] = u.v;
            }
        }
    } else {
        #pragma unroll
        for (int c = 0; c < 8; ++c) kr[c] = make_uint4(0u, 0u, 0u, 0u);
    }

    const int qi = query[b];
    if (tid < 8) {
        uint4 qv;
        if (use16) {
            qv = ((const uint4*)(emb16 + (size_t)qi * E))[tid];
        } else {
            const float4 x = ((const float4*)(embf + (size_t)qi * E))[2 * tid];
            const float4 y = ((const float4*)(embf + (size_t)qi * E))[2 * tid + 1];
            union { bf16_t h[8]; uint4 v; } u;
            u.h[0] = (bf16_t)x.x; u.h[1] = (bf16_t)x.y; u.h[2] = (bf16_t)x.z; u.h[3] = (bf16_t)x.w;
            u.h[4] = (bf16_t)y.x; u.h[5] = (bf16_t)y.y; u.h[6] = (bf16_t)y.z; u.h[7] = (bf16_t)y.w;
            qv = u.v;
        }
        ((uint4*)sQtmp)[tid] = qv;
    }
    if (tid < 64) sW2f[tid] = w2[tid];
    __syncthreads();
    if (tid < 64) sQf[tid] = (float)((const bf16_t*)sQtmp)[tid];
    __syncthreads();

    {
        float* sTmp = (float*)sRaw;
        const int j = tid & 63, ec = tid >> 6;
        float au = 0.f;
        #pragma unroll
        for (int eo = 0; eo < 16; ++eo) {
            const int e = ec * 16 + eo;
            const float w1a = w1[e * 64 + j];
            const float w1b = w1[(64 + e) * 64 + j];
            const float w1c = w1[(128 + e) * 64 + j];
            const float w1d = w1[(192 + e) * 64 + j];
            sTmp[e * 65 + j] = w1b - w1c + sQf[e] * w1d;
            au = fmaf(sQf[e], w1a + w1c, au);
        }
        sUP[tid] = au;
    }
    __syncthreads();
    {
        const float* sTmp = (const float*)sRaw;
        const int e = tid & 63, jc = tid >> 6;
        #pragma unroll
        for (int jo = 0; jo < 16; ++jo) {
            const int j = jc * 16 + jo;
            sMt[j * ROW + e] = (bf16_t)sTmp[e * 65 + j];
        }
    }
    if (tid < 64) sU[tid] = b1[tid] + sUP[tid] + sUP[64 + tid] + sUP[128 + tid] + sUP[192 + tid];
    __syncthreads();

    bf16_t* sK = (bf16_t*)sRaw;
    {
        uint4* dst = (uint4*)(sK + tid * ROW);
        #pragma unroll
        for (int c = 0; c < 8; ++c) dst[c] = kr[c];
    }
    __syncthreads();

    {
        const int n    = lane & 15;
        const int quad = lane >> 4;
        float w2v[4], uv[4];
        bf16x8 bF[4][2];
        #pragma unroll
        for (int nt = 0; nt < 4; ++nt) {
            w2v[nt] = sW2f[nt * 16 + n];
            uv[nt]  = sU[nt * 16 + n];
            bF[nt][0] = *(const bf16x8*)&sMt[(nt * 16 + n) * ROW + quad * 8];
            bF[nt][1] = *(const bf16x8*)&sMt[(nt * 16 + n) * ROW + 32 + quad * 8];
        }
        #pragma unroll
        for (int i = 0; i < 4; ++i) {
            const int mt = wid * 4 + i;
            const bf16x8 a0 = *(const bf16x8*)&sK[(mt * 16 + n) * ROW + quad * 8];
            const bf16x8 a1 = *(const bf16x8*)&sK[(mt * 16 + n) * ROW + 32 + quad * 8];
            float s0 = 0.f, s1 = 0.f, s2 = 0.f, s3 = 0.f;
            #pragma unroll
            for (int nt = 0; nt < 4; ++nt) {
                f32x4 acc = { uv[nt], uv[nt], uv[nt], uv[nt] };
                acc = __builtin_amdgcn_mfma_f32_16x16x32_bf16(a0, bF[nt][0], acc, 0, 0, 0);
                acc = __builtin_amdgcn_mfma_f32_16x16x32_bf16(a1, bF[nt][1], acc, 0, 0, 0);
                s0 = fmaf(fmaxf(acc[0], 0.f), w2v[nt], s0);
                s1 = fmaf(fmaxf(acc[1], 0.f), w2v[nt], s1);
                s2 = fmaf(fmaxf(acc[2], 0.f), w2v[nt], s2);
                s3 = fmaf(fmaxf(acc[3], 0.f), w2v[nt], s3);
            }
            #pragma unroll
            for (int off = 1; off < 16; off <<= 1) {
                s0 += __shfl_xor(s0, off);
                s1 += __shfl_xor(s1, off);
                s2 += __shfl_xor(s2, off);
                s3 += __shfl_xor(s3, off);
            }
            if (n == 0) {
                const int base = mt * 16 + quad * 4;
                sWgt[base + 0] = s0;
                sWgt[base + 1] = s1;
                sWgt[base + 2] = s2;
                sWgt[base + 3] = s3;
            }
        }
    }
    __syncthreads();

    {
        const float score = (tid < T) ? (sWgt[tid] + b2v) : -1e30f;
        float m = score;
        #pragma unroll
        for (int off = 32; off > 0; off >>= 1) m = fmaxf(m, __shfl_xor(m, off));
        if (lane == 0) sRed[wid] = m;
        __syncthreads();
        const float gmax = fmaxf(fmaxf(sRed[0], sRed[1]), fmaxf(sRed[2], sRed[3]));
        const float p = (tid < T) ? __expf(score - gmax) : 0.f;
        float s = p;
        #pragma unroll
        for (int off = 32; off > 0; off >>= 1) s += __shfl_xor(s, off);
        if (lane == 0) sRed[4 + wid] = s;
        __syncthreads();
        const float gsum = sRed[4] + sRed[5] + sRed[6] + sRed[7];
        sWgt[tid] = p / gsum;
    }
    __syncthreads();

    {
        const int e = tid & 63, ch = tid >> 6;
        float a = 0.f;
        #pragma unroll 8
        for (int tt = 0; tt < 64; ++tt) {
            const int t = ch * 64 + tt;
            a = fmaf(sWgt[t], (float)sK[t * ROW + e], a);
        }
        sUP[tid] = a;
    }
    __syncthreads();
    if (tid < 64) sInt[tid] = sUP[tid] + sUP[64 + tid] + sUP[128 + tid] + sUP[192 + tid];
    __syncthreads();

    if (tid < 128) {
        float a = db1[tid];
        #pragma unroll 8
        for (int e = 0; e < 64; ++e) a = fmaf(sInt[e], dw1[e * 128 + tid], a);
        sD1[tid] = fmaxf(a, 0.f);
    }
    __syncthreads();
    if (tid < 64) {
        float a = db2[tid];
        #pragma unroll 8
        for (int i = 0; i < 128; ++i) a = fmaf(sD1[i], dw2[i * 64 + tid], a);
        sD2[tid] = fmaxf(a, 0.f);
    }
    __syncthreads();
    if (tid < 64) {
        float v = sD2[tid] * ow[tid];
        #pragma unroll
        for (int off = 32; off > 0; off >>= 1) v += __shfl_xor(v, off);
        if (tid == 0) out[b] = 1.f / (1.f + __expf(-(v + ob[0])));
    }
}

extern "C" void kernel_launch(void* const* d_in, const int* in_sizes, int n_in,
                              void* d_out, int out_size, void* d_ws, size_t ws_size,
                              hipStream_t stream) {
    const int*   query = (const int*)d_in[0];
    const int*   keys  = (const int*)d_in[1];
    const float* embf  = (const float*)d_in[2];
    const float* w1    = (const float*)d_in[3];
    const float* b1    = (const float*)d_in[4];
    const float* w2    = (const float*)d_in[5];
    const float* b2    = (const float*)d_in[6];
    const float* dw1   = (const float*)d_in[7];
    const float* db1   = (const float*)d_in[8];
    const float* dw2   = (const float*)d_in[9];
    const float* db2   = (const float*)d_in[10];
    const float* ow    = (const float*)d_in[11];
    const float* ob    = (const float*)d_in[12];
    float* out = (float*)d_out;
    const int B        = in_sizes[0];
    const int embElems = in_sizes[2];                  // VOCAB * E
    const size_t WOFF  = 49152;                        // Ap 16K | Ctf 16K | Dtf 16K

    if (ws_size >= WOFF + (size_t)embElems * 2) {
        float*  Ap    = (float*)d_ws;
        float*  Ctf   = (float*)((char*)d_ws + 16384);
        float*  Dtf   = (float*)((char*)d_ws + 32768);
        bf16_t* emb16 = (bf16_t*)((char*)d_ws + WOFF);
        const int n8 = embElems / 8;
        w1_cvt<<<16, 256, 0, stream>>>(w1, Ap, Ctf, Dtf);
        emb_cvt<<<(n8 + 255) / 256, 256, 0, stream>>>(embf, emb16, n8);
        din_fast<<<B, BDIM, 0, stream>>>(query, keys, emb16, Ap, Ctf, Dtf,
                                         b1, w2, b2, dw1, db1, dw2, db2, ow, ob, out);
    } else {
        const int use16 = (ws_size >= (size_t)embElems * 2) ? 1 : 0;
        bf16_t* emb16 = (bf16_t*)d_ws;
        if (use16) {
            const int n8 = embElems / 8;
            emb_cvt<<<(n8 + 255) / 256, 256, 0, stream>>>(embf, emb16, n8);
        }
        din_kernel<<<B, BDIM, 0, stream>>>(query, keys, embf, emb16, use16,
                                           w1, b1, w2, b2, dw1, db1, dw2, db2, ow, ob, out);
    }
}

// Round 7
// 170.457 us; speedup vs baseline: 1.3461x; 1.2141x over previous
//
#include <hip/hip_runtime.h>

#define T 200
#define E 64
#define TPAD 256
#define ROW 72          // bf16 elems per padded LDS row (144 B, 16B-aligned)
#define BDIM 256
#define TP 208          // padded A-tile rows (13 m-tiles)

typedef __bf16 bf16_t;
typedef __bf16 bf16x8 __attribute__((ext_vector_type(8)));
typedef float f32x4 __attribute__((ext_vector_type(4)));

// ---- pre-pass: fold w1 into batch-independent pieces (fp32, exact) ----
//  Ap [e][j]  = w1a + w1c            (for u = q @ Ap)
//  Ctf[j][e]  = w1b - w1c            (M^T additive part)
//  Dtf[j][e]  = w1d                  (M^T q-scaled part)
__global__ __launch_bounds__(256) void w1_cvt(const float* __restrict__ w1,
                                              float* __restrict__ Ap,
                                              float* __restrict__ Ctf,
                                              float* __restrict__ Dtf) {
    const int idx = blockIdx.x * 256 + threadIdx.x;   // 0..4095
    const int e = idx >> 6, j = idx & 63;
    const float a = w1[e * 64 + j];
    const float b = w1[(64 + e) * 64 + j];
    const float c = w1[(128 + e) * 64 + j];
    const float d = w1[(192 + e) * 64 + j];
    Ap[e * 64 + j]  = a + c;
    Ctf[j * 64 + e] = b - c;
    Dtf[j * 64 + e] = d;
}

// ===== fast kernel: exact R2 structure (76 µs, 52 VGPR, no spill), but =====
// ===== gathers fp32 emb directly (emb_cvt pre-pass DELETED this round) =====
// 39936 B LDS -> 4 blocks/CU. kr converted fp32->bf16 in-register (same math
// as the old emb_cvt, bitwise identical); query row kept fp32 (closer to ref).
__global__ __launch_bounds__(256, 4) void din_fast(
    const int* __restrict__ query,
    const int* __restrict__ keys,
    const float* __restrict__ embf,
    const float* __restrict__ Ap,
    const float* __restrict__ Ctf,
    const float* __restrict__ Dtf,
    const float* __restrict__ b1,
    const float* __restrict__ w2,
    const float* __restrict__ b2,
    const float* __restrict__ dw1,
    const float* __restrict__ db1,
    const float* __restrict__ dw2,
    const float* __restrict__ db2,
    const float* __restrict__ ow,
    const float* __restrict__ ob,
    float* __restrict__ out)
{
    // manual LDS packing: total 39936 B (floor(163840/39936) = 4 blocks/CU)
    __shared__ __align__(16) char smem[39936];
    bf16_t* sK   = (bf16_t*)smem;                 // [0,29952)  208x72 bf16 A-tile
    bf16_t* sMt  = (bf16_t*)(smem + 29952);       // [29952,39168) 64x72 bf16 B-op (M^T)
    float*  sUP  = (float*)(smem + 39168);        // [39168,39680) u partials (128)
    float*  sQf  = (float*)(smem + 39680);        // [39680,39936) q fp32 (64)
    // overlays inside sMt region (dead after B-frag load barrier):
    float*  sWgt = (float*)(smem + 29952);        // 208 scores/weights
    float*  sRed = (float*)(smem + 30784);        // 8
    float*  sInt = (float*)(smem + 30816);        // 64
    float*  sD1  = (float*)(smem + 31072);        // 128
    float*  sD2  = (float*)(smem + 31584);        // 64
    float*  sIP  = (float*)(smem + 31840);        // 256 interest partials

    const int tid  = threadIdx.x;
    const int lane = tid & 63;
    const int wid  = tid >> 6;
    const int b    = blockIdx.x;
    const float b2v = b2[0];

    // ---- issue long-latency gathers first: this thread's key row (t = tid) ----
    // fp32 row (256 B), converted to bf16 in-register (identical to old emb_cvt)
    uint4 kr[8];
    if (tid < T) {
        const int ki = keys[b * T + tid];
        const float4* kp = (const float4*)(embf + (size_t)ki * E);
        #pragma unroll
        for (int c = 0; c < 8; ++c) {
            const float4 x = kp[2 * c], y = kp[2 * c + 1];
            union { bf16_t h[8]; uint4 v; } u;
            u.h[0] = (bf16_t)x.x; u.h[1] = (bf16_t)x.y; u.h[2] = (bf16_t)x.z; u.h[3] = (bf16_t)x.w;
            u.h[4] = (bf16_t)y.x; u.h[5] = (bf16_t)y.y; u.h[6] = (bf16_t)y.z; u.h[7] = (bf16_t)y.w;
            kr[c] = u.v;
        }
    } else {
        #pragma unroll
        for (int c = 0; c < 8; ++c) kr[c] = make_uint4(0u, 0u, 0u, 0u);
    }

    // ---- query row (fp32 direct, 64 lanes = 256B coalesced) ----
    const int qi = query[b];
    if (tid < 64) sQf[tid] = embf[(size_t)qi * E + tid];
    __syncthreads();                                   // B0: sQf ready

    // ---- u partials (tid<128): u[j] = sum_e q[e] * Ap[e][j] ----
    if (tid < 128) {
        const int j = tid & 63, ec = tid >> 6;
        float au = 0.f;
        #pragma unroll
        for (int eo = 0; eo < 32; ++eo) {
            const int e = ec * 32 + eo;
            au = fmaf(sQf[e], Ap[e * 64 + j], au);
        }
        sUP[tid] = au;
    }
    // ---- build M^T directly into sMt (no transpose scratch, no w1 reads) ----
    {
        const int j = tid & 63, h = tid >> 6;          // h: 16-col chunk
        const float* cp = Ctf + j * 64 + h * 16;
        const float* dp = Dtf + j * 64 + h * 16;
        const float* qp = sQf + h * 16;
        bf16_t mo[16] __attribute__((aligned(16)));
        #pragma unroll
        for (int x = 0; x < 16; ++x)
            mo[x] = (bf16_t)fmaf(qp[x], dp[x], cp[x]);
        *(bf16x8*)&sMt[j * ROW + h * 16]     = *(bf16x8*)&mo[0];
        *(bf16x8*)&sMt[j * ROW + h * 16 + 8] = *(bf16x8*)&mo[8];
    }
    __syncthreads();                                   // B1: sUP, sMt ready

    // ---- stage k rows into sK (gathers have had B0..B1 to land) ----
    if (tid < TP) {
        uint4* dst = (uint4*)(sK + tid * ROW);
        #pragma unroll
        for (int c = 0; c < 8; ++c) dst[c] = kr[c];
    }
    __syncthreads();                                   // B2: sK ready

    // ---- MFMA score GEMM: h_pre = u + k(208x64) * M(64x64) ----
    {
        const int n    = lane & 15;
        const int quad = lane >> 4;
        float w2v[4], uv[4];
        bf16x8 bF[4][2];
        #pragma unroll
        for (int nt = 0; nt < 4; ++nt) {
            const int jj = nt * 16 + n;
            w2v[nt] = w2[jj];
            uv[nt]  = b1[jj] + sUP[jj] + sUP[64 + jj];
            bF[nt][0] = *(const bf16x8*)&sMt[jj * ROW + quad * 8];
            bF[nt][1] = *(const bf16x8*)&sMt[jj * ROW + 32 + quad * 8];
        }
        __syncthreads();                               // B3: sMt/sUP now dead -> overlays safe

        for (int mt = wid; mt < 13; mt += 4) {
            const bf16x8 a0 = *(const bf16x8*)&sK[(mt * 16 + n) * ROW + quad * 8];
            const bf16x8 a1 = *(const bf16x8*)&sK[(mt * 16 + n) * ROW + 32 + quad * 8];
            float s0 = 0.f, s1 = 0.f, s2 = 0.f, s3 = 0.f;
            #pragma unroll
            for (int nt = 0; nt < 4; ++nt) {
                f32x4 acc = { uv[nt], uv[nt], uv[nt], uv[nt] };
                acc = __builtin_amdgcn_mfma_f32_16x16x32_bf16(a0, bF[nt][0], acc, 0, 0, 0);
                acc = __builtin_amdgcn_mfma_f32_16x16x32_bf16(a1, bF[nt][1], acc, 0, 0, 0);
                s0 = fmaf(fmaxf(acc[0], 0.f), w2v[nt], s0);
                s1 = fmaf(fmaxf(acc[1], 0.f), w2v[nt], s1);
                s2 = fmaf(fmaxf(acc[2], 0.f), w2v[nt], s2);
                s3 = fmaf(fmaxf(acc[3], 0.f), w2v[nt], s3);
            }
            #pragma unroll
            for (int off = 1; off < 16; off <<= 1) {
                s0 += __shfl_xor(s0, off);
                s1 += __shfl_xor(s1, off);
                s2 += __shfl_xor(s2, off);
                s3 += __shfl_xor(s3, off);
            }
            if (n == 0) {
                const int base = mt * 16 + quad * 4;
                sWgt[base + 0] = s0;
                sWgt[base + 1] = s1;
                sWgt[base + 2] = s2;
                sWgt[base + 3] = s3;
            }
        }
    }
    __syncthreads();                                   // B4

    // ---- softmax over t ----
    {
        const float score = (tid < T) ? (sWgt[tid] + b2v) : -1e30f;
        float m = score;
        #pragma unroll
        for (int off = 32; off > 0; off >>= 1) m = fmaxf(m, __shfl_xor(m, off));
        if (lane == 0) sRed[wid] = m;
        __syncthreads();                               // B5
        const float gmax = fmaxf(fmaxf(sRed[0], sRed[1]), fmaxf(sRed[2], sRed[3]));
        const float p = (tid < T) ? __expf(score - gmax) : 0.f;
        float s = p;
        #pragma unroll
        for (int off = 32; off > 0; off >>= 1) s += __shfl_xor(s, off);
        if (lane == 0) sRed[4 + wid] = s;
        __syncthreads();                               // B6
        const float gsum = sRed[4] + sRed[5] + sRed[6] + sRed[7];
        if (tid < T) sWgt[tid] = p / gsum;
    }
    __syncthreads();                                   // B7

    // ---- interest[e] = sum_t w[t] * k[t][e]  (t<200 only, 4x50 chunks) ----
    {
        const int e = tid & 63, ch = tid >> 6;
        float a = 0.f;
        #pragma unroll 10
        for (int tt = 0; tt < 50; ++tt) {
            const int t = ch * 50 + tt;
            a = fmaf(sWgt[t], (float)sK[t * ROW + e], a);
        }
        sIP[tid] = a;
    }
    __syncthreads();                                   // B8
    if (tid < 64) sInt[tid] = sIP[tid] + sIP[64 + tid] + sIP[128 + tid] + sIP[192 + tid];
    __syncthreads();                                   // B9

    // ---- deep MLP: 64 -> 128 -> 64 -> 1 ----
    if (tid < 128) {
        float a = db1[tid];
        #pragma unroll 8
        for (int e = 0; e < 64; ++e) a = fmaf(sInt[e], dw1[e * 128 + tid], a);
        sD1[tid] = fmaxf(a, 0.f);
    }
    __syncthreads();                                   // B10
    if (tid < 64) {
        float a = db2[tid];
        #pragma unroll 8
        for (int i = 0; i < 128; ++i) a = fmaf(sD1[i], dw2[i * 64 + tid], a);
        sD2[tid] = fmaxf(a, 0.f);
    }
    __syncthreads();                                   // B11
    if (tid < 64) {
        float v = sD2[tid] * ow[tid];
        #pragma unroll
        for (int off = 32; off > 0; off >>= 1) v += __shfl_xor(v, off);
        if (tid == 0) out[b] = 1.f / (1.f + __expf(-(v + ob[0])));
    }
}

// ============ fallback: previous verified kernel (ws too small) ============
__global__ __launch_bounds__(BDIM, 3) void din_kernel(
    const int* __restrict__ query,
    const int* __restrict__ keys,
    const float* __restrict__ embf,
    const bf16_t* __restrict__ emb16,
    const int use16,
    const float* __restrict__ w1,
    const float* __restrict__ b1,
    const float* __restrict__ w2,
    const float* __restrict__ b2,
    const float* __restrict__ dw1,
    const float* __restrict__ db1,
    const float* __restrict__ dw2,
    const float* __restrict__ db2,
    const float* __restrict__ ow,
    const float* __restrict__ ob,
    float* __restrict__ out)
{
    __shared__ __align__(16) char sRaw[TPAD * ROW * 2];
    __shared__ __align__(16) bf16_t sMt[64 * ROW];
    __shared__ float sU[64];
    __shared__ float sUP[256];
    __shared__ float sW2f[64];
    __shared__ float sWgt[256];
    __shared__ float sQf[64];
    __shared__ __align__(16) char sQtmp[128];
    __shared__ float sRed[8];
    __shared__ float sInt[64];
    __shared__ float sD1[128];
    __shared__ float sD2[64];

    const int tid  = threadIdx.x;
    const int lane = tid & 63;
    const int wid  = tid >> 6;
    const int b    = blockIdx.x;
    const float b2v = b2[0];

    uint4 kr[8];
    if (tid < T) {
        const int ki = keys[b * T + tid];
        if (use16) {
            const uint4* kp = (const uint4*)(emb16 + (size_t)ki * E);
            #pragma unroll
            for (int c = 0; c < 8; ++c) kr[c] = kp[c];
        } else {
            const float4* kp = (const float4*)(embf + (size_t)ki * E);
            #pragma unroll
            for (int c = 0; c < 8; ++c) {
                const float4 x = kp[2 * c], y = kp[2 * c + 1];
                union { bf16_t h[8]; uint4 v; } u;
                u.h[0] = (bf16_t)x.x; u.h[1] = (bf16_t)x.y; u.h[2] = (bf16_t)x.z; u.h[3] = (bf16_t)x.w;
                u.h[4] = (bf16_t)y.x; u.h[5] = (bf16_t)y.y; u.h[6] = (bf16_t)y.z; u.h[7] = (bf16_t)y.w;
                kr[c] = u.v;
            }
        }
    } else {
        #pragma unroll
        for (int c = 0; c < 8; ++c) kr[c] = make_uint4(0u, 0u, 0u, 0u);
    }

    const int qi = query[b];
    if (tid < 8) {
        uint4 qv;
        if (use16) {
            qv = ((const uint4*)(emb16 + (size_t)qi * E))[tid];
        } else {
            const float4 x = ((const float4*)(embf + (size_t)qi * E))[2 * tid];
            const float4 y = ((const float4*)(embf + (size_t)qi * E))[2 * tid + 1];
            union { bf16_t h[8]; uint4 v; } u;
            u.h[0] = (bf16_t)x.x; u.h[1] = (bf16_t)x.y; u.h[2] = (bf16_t)x.z; u.h[3] = (bf16_t)x.w;
            u.h[4] = (bf16_t)y.x; u.h[5] = (bf16_t)y.y; u.h[6] = (bf16_t)y.z; u.h[7] = (bf16_t)y.w;
            qv = u.v;
        }
        ((uint4*)sQtmp)[tid] = qv;
    }
    if (tid < 64) sW2f[tid] = w2[tid];
    __syncthreads();
    if (tid < 64) sQf[tid] = (float)((const bf16_t*)sQtmp)[tid];
    __syncthreads();

    {
        float* sTmp = (float*)sRaw;
        const int j = tid & 63, ec = tid >> 6;
        float au = 0.f;
        #pragma unroll
        for (int eo = 0; eo < 16; ++eo) {
            const int e = ec * 16 + eo;
            const float w1a = w1[e * 64 + j];
            const float w1b = w1[(64 + e) * 64 + j];
            const float w1c = w1[(128 + e) * 64 + j];
            const float w1d = w1[(192 + e) * 64 + j];
            sTmp[e * 65 + j] = w1b - w1c + sQf[e] * w1d;
            au = fmaf(sQf[e], w1a + w1c, au);
        }
        sUP[tid] = au;
    }
    __syncthreads();
    {
        const float* sTmp = (const float*)sRaw;
        const int e = tid & 63, jc = tid >> 6;
        #pragma unroll
        for (int jo = 0; jo < 16; ++jo) {
            const int j = jc * 16 + jo;
            sMt[j * ROW + e] = (bf16_t)sTmp[e * 65 + j];
        }
    }
    if (tid < 64) sU[tid] = b1[tid] + sUP[tid] + sUP[64 + tid] + sUP[128 + tid] + sUP[192 + tid];
    __syncthreads();

    bf16_t* sK = (bf16_t*)sRaw;
    {
        uint4* dst = (uint4*)(sK + tid * ROW);
        #pragma unroll
        for (int c = 0; c < 8; ++c) dst[c] = kr[c];
    }
    __syncthreads();

    {
        const int n    = lane & 15;
        const int quad = lane >> 4;
        float w2v[4], uv[4];
        bf16x8 bF[4][2];
        #pragma unroll
        for (int nt = 0; nt < 4; ++nt) {
            w2v[nt] = sW2f[nt * 16 + n];
            uv[nt]  = sU[nt * 16 + n];
            bF[nt][0] = *(const bf16x8*)&sMt[(nt * 16 + n) * ROW + quad * 8];
            bF[nt][1] = *(const bf16x8*)&sMt[(nt * 16 + n) * ROW + 32 + quad * 8];
        }
        #pragma unroll
        for (int i = 0; i < 4; ++i) {
            const int mt = wid * 4 + i;
            const bf16x8 a0 = *(const bf16x8*)&sK[(mt * 16 + n) * ROW + quad * 8];
            const bf16x8 a1 = *(const bf16x8*)&sK[(mt * 16 + n) * ROW + 32 + quad * 8];
            float s0 = 0.f, s1 = 0.f, s2 = 0.f, s3 = 0.f;
            #pragma unroll
            for (int nt = 0; nt < 4; ++nt) {
                f32x4 acc = { uv[nt], uv[nt], uv[nt], uv[nt] };
                acc = __builtin_amdgcn_mfma_f32_16x16x32_bf16(a0, bF[nt][0], acc, 0, 0, 0);
                acc = __builtin_amdgcn_mfma_f32_16x16x32_bf16(a1, bF[nt][1], acc, 0, 0, 0);
                s0 = fmaf(fmaxf(acc[0], 0.f), w2v[nt], s0);
                s1 = fmaf(fmaxf(acc[1], 0.f), w2v[nt], s1);
                s2 = fmaf(fmaxf(acc[2], 0.f), w2v[nt], s2);
                s3 = fmaf(fmaxf(acc[3], 0.f), w2v[nt], s3);
            }
            #pragma unroll
            for (int off = 1; off < 16; off <<= 1) {
                s0 += __shfl_xor(s0, off);
                s1 += __shfl_xor(s1, off);
                s2 += __shfl_xor(s2, off);
                s3 += __shfl_xor(s3, off);
            }
            if (n == 0) {
                const int base = mt * 16 + quad * 4;
                sWgt[base + 0] = s0;
                sWgt[base + 1] = s1;
                sWgt[base + 2] = s2;
                sWgt[base + 3] = s3;
            }
        }
    }
    __syncthreads();

    {
        const float score = (tid < T) ? (sWgt[tid] + b2v) : -1e30f;
        float m = score;
        #pragma unroll
        for (int off = 32; off > 0; off >>= 1) m = fmaxf(m, __shfl_xor(m, off));
        if (lane == 0) sRed[wid] = m;
        __syncthreads();
        const float gmax = fmaxf(fmaxf(sRed[0], sRed[1]), fmaxf(sRed[2], sRed[3]));
        const float p = (tid < T) ? __expf(score - gmax) : 0.f;
        float s = p;
        #pragma unroll
        for (int off = 32; off > 0; off >>= 1) s += __shfl_xor(s, off);
        if (lane == 0) sRed[4 + wid] = s;
        __syncthreads();
        const float gsum = sRed[4] + sRed[5] + sRed[6] + sRed[7];
        sWgt[tid] = p / gsum;
    }
    __syncthreads();

    {
        const int e = tid & 63, ch = tid >> 6;
        float a = 0.f;
        #pragma unroll 8
        for (int tt = 0; tt < 64; ++tt) {
            const int t = ch * 64 + tt;
            a = fmaf(sWgt[t], (float)sK[t * ROW + e], a);
        }
        sUP[tid] = a;
    }
    __syncthreads();
    if (tid < 64) sInt[tid] = sUP[tid] + sUP[64 + tid] + sUP[128 + tid] + sUP[192 + tid];
    __syncthreads();

    if (tid < 128) {
        float a = db1[tid];
        #pragma unroll 8
        for (int e = 0; e < 64; ++e) a = fmaf(sInt[e], dw1[e * 128 + tid], a);
        sD1[tid] = fmaxf(a, 0.f);
    }
    __syncthreads();
    if (tid < 64) {
        float a = db2[tid];
        #pragma unroll 8
        for (int i = 0; i < 128; ++i) a = fmaf(sD1[i], dw2[i * 64 + tid], a);
        sD2[tid] = fmaxf(a, 0.f);
    }
    __syncthreads();
    if (tid < 64) {
        float v = sD2[tid] * ow[tid];
        #pragma unroll
        for (int off = 32; off > 0; off >>= 1) v += __shfl_xor(v, off);
        if (tid == 0) out[b] = 1.f / (1.f + __expf(-(v + ob[0])));
    }
}

extern "C" void kernel_launch(void* const* d_in, const int* in_sizes, int n_in,
                              void* d_out, int out_size, void* d_ws, size_t ws_size,
                              hipStream_t stream) {
    const int*   query = (const int*)d_in[0];
    const int*   keys  = (const int*)d_in[1];
    const float* embf  = (const float*)d_in[2];
    const float* w1    = (const float*)d_in[3];
    const float* b1    = (const float*)d_in[4];
    const float* w2    = (const float*)d_in[5];
    const float* b2    = (const float*)d_in[6];
    const float* dw1   = (const float*)d_in[7];
    const float* db1   = (const float*)d_in[8];
    const float* dw2   = (const float*)d_in[9];
    const float* db2   = (const float*)d_in[10];
    const float* ow    = (const float*)d_in[11];
    const float* ob    = (const float*)d_in[12];
    float* out = (float*)d_out;
    const int B = in_sizes[0];

    if (ws_size >= 49152) {                            // Ap 16K | Ctf 16K | Dtf 16K
        float* Ap  = (float*)d_ws;
        float* Ctf = (float*)((char*)d_ws + 16384);
        float* Dtf = (float*)((char*)d_ws + 32768);
        w1_cvt<<<16, 256, 0, stream>>>(w1, Ap, Ctf, Dtf);
        din_fast<<<B, BDIM, 0, stream>>>(query, keys, embf, Ap, Ctf, Dtf,
                                         b1, w2, b2, dw1, db1, dw2, db2, ow, ob, out);
    } else {
        din_kernel<<<B, BDIM, 0, stream>>>(query, keys, embf, (const bf16_t*)d_ws, 0,
                                           w1, b1, w2, b2, dw1, db1, dw2, db2, ow, ob, out);
    }
}

// Round 8
// 167.066 us; speedup vs baseline: 1.3735x; 1.0203x over previous
//
#include <hip/hip_runtime.h>

#define T 200
#define E 64
#define TPAD 256
#define ROW 72          // bf16 elems per padded LDS row (144 B, 16B-aligned)
#define BDIM 256
#define TP 208          // padded A-tile rows (13 m-tiles)

typedef __bf16 bf16_t;
typedef __bf16 bf16x8 __attribute__((ext_vector_type(8)));
typedef float f32x4 __attribute__((ext_vector_type(4)));

// ---- merged pre-pass: blocks 0..15 fold w1; blocks 16.. convert emb ----
__global__ __launch_bounds__(256) void pre_cvt(const float* __restrict__ embf,
                                               bf16_t* __restrict__ emb16, int n8,
                                               const float* __restrict__ w1,
                                               float* __restrict__ Ap,
                                               float* __restrict__ Ctf,
                                               float* __restrict__ Dtf) {
    const int bid = blockIdx.x;
    if (bid < 16) {
        // w1 fold: Ap[e][j]=a+c, Ctf[j][e]=b-c, Dtf[j][e]=d   (fp32, exact)
        const int idx = bid * 256 + threadIdx.x;      // 0..4095
        const int e = idx >> 6, j = idx & 63;
        const float a = w1[e * 64 + j];
        const float b = w1[(64 + e) * 64 + j];
        const float c = w1[(128 + e) * 64 + j];
        const float d = w1[(192 + e) * 64 + j];
        Ap[e * 64 + j]  = a + c;
        Ctf[j * 64 + e] = b - c;
        Dtf[j * 64 + e] = d;
        return;
    }
    const int i = (bid - 16) * 256 + threadIdx.x;
    if (i >= n8) return;
    const float4* s = (const float4*)embf + (size_t)i * 2;
    const float4 a = s[0], b = s[1];
    union { bf16_t h[8]; uint4 v; } u;
    u.h[0] = (bf16_t)a.x; u.h[1] = (bf16_t)a.y; u.h[2] = (bf16_t)a.z; u.h[3] = (bf16_t)a.w;
    u.h[4] = (bf16_t)b.x; u.h[5] = (bf16_t)b.y; u.h[6] = (bf16_t)b.z; u.h[7] = (bf16_t)b.w;
    ((uint4*)emb16)[i] = u.v;
}

// ===== fast kernel: R2 structure (76 µs, 52 VGPR, no spill) + transposed =====
// ===== cooperative gather: 8 lanes/row x 16B -> coalesced 128B segments  =====
// 39936 B LDS -> 4 blocks/CU.
__global__ __launch_bounds__(256, 4) void din_fast(
    const int* __restrict__ query,
    const int* __restrict__ keys,
    const bf16_t* __restrict__ emb16,
    const float* __restrict__ Ap,
    const float* __restrict__ Ctf,
    const float* __restrict__ Dtf,
    const float* __restrict__ b1,
    const float* __restrict__ w2,
    const float* __restrict__ b2,
    const float* __restrict__ dw1,
    const float* __restrict__ db1,
    const float* __restrict__ dw2,
    const float* __restrict__ db2,
    const float* __restrict__ ow,
    const float* __restrict__ ob,
    float* __restrict__ out)
{
    // manual LDS packing: total 39936 B (floor(163840/39936) = 4 blocks/CU)
    __shared__ __align__(16) char smem[39936];
    bf16_t* sK   = (bf16_t*)smem;                 // [0,29952)  208x72 bf16 A-tile
    bf16_t* sMt  = (bf16_t*)(smem + 29952);       // [29952,39168) 64x72 bf16 B-op (M^T)
    float*  sUP  = (float*)(smem + 39168);        // [39168,39680) u partials (128)
    float*  sQf  = (float*)(smem + 39680);        // [39680,39936) q fp32 (64)
    // overlays inside sMt region (dead after B-frag load barrier):
    float*  sWgt = (float*)(smem + 29952);        // 208 scores/weights
    float*  sRed = (float*)(smem + 30784);        // 8
    float*  sInt = (float*)(smem + 30816);        // 64
    float*  sD1  = (float*)(smem + 31072);        // 128
    float*  sD2  = (float*)(smem + 31584);        // 64
    float*  sIP  = (float*)(smem + 31840);        // 256 interest partials

    const int tid  = threadIdx.x;
    const int lane = tid & 63;
    const int wid  = tid >> 6;
    const int b    = blockIdx.x;
    const float b2v = b2[0];

    // ---- transposed cooperative gather: row = (tid>>3)+32*i, chunk = tid&7 ----
    // Each instruction: 64 lanes cover 8 contiguous 128B rows (vs 64 scattered).
    const int c8    = tid & 7;
    const int rbase = tid >> 3;                        // 0..31
    uint4 kr[7];
    #pragma unroll
    for (int i = 0; i < 7; ++i) {
        const int t = rbase + 32 * i;                  // 0..223
        if (t < T) {
            const int ki = keys[b * T + t];
            kr[i] = ((const uint4*)(emb16 + (size_t)ki * E))[c8];
        } else {
            kr[i] = make_uint4(0u, 0u, 0u, 0u);
        }
    }

    // ---- query row (bf16 scalar, 64 lanes = 128B coalesced) ----
    const int qi = query[b];
    if (tid < 64) sQf[tid] = (float)emb16[(size_t)qi * E + tid];
    __syncthreads();                                   // B0: sQf ready

    // ---- u partials (tid<128): u[j] = sum_e q[e] * Ap[e][j] ----
    if (tid < 128) {
        const int j = tid & 63, ec = tid >> 6;
        float au = 0.f;
        #pragma unroll
        for (int eo = 0; eo < 32; ++eo) {
            const int e = ec * 32 + eo;
            au = fmaf(sQf[e], Ap[e * 64 + j], au);
        }
        sUP[tid] = au;
    }
    // ---- build M^T directly into sMt ----
    {
        const int j = tid & 63, h = tid >> 6;          // h: 16-col chunk
        const float* cp = Ctf + j * 64 + h * 16;
        const float* dp = Dtf + j * 64 + h * 16;
        const float* qp = sQf + h * 16;
        bf16_t mo[16] __attribute__((aligned(16)));
        #pragma unroll
        for (int x = 0; x < 16; ++x)
            mo[x] = (bf16_t)fmaf(qp[x], dp[x], cp[x]);
        *(bf16x8*)&sMt[j * ROW + h * 16]     = *(bf16x8*)&mo[0];
        *(bf16x8*)&sMt[j * ROW + h * 16 + 8] = *(bf16x8*)&mo[8];
    }
    __syncthreads();                                   // B1: sUP, sMt ready

    // ---- stage k rows into sK (transposed; rows 200..207 zeroed for tile 12) ----
    #pragma unroll
    for (int i = 0; i < 7; ++i) {
        const int t = rbase + 32 * i;
        if (t < TP) *(uint4*)&sK[t * ROW + c8 * 8] = kr[i];
    }
    __syncthreads();                                   // B2: sK ready

    // ---- MFMA score GEMM: h_pre = u + k(208x64) * M(64x64) ----
    {
        const int n    = lane & 15;
        const int quad = lane >> 4;
        float w2v[4], uv[4];
        bf16x8 bF[4][2];
        #pragma unroll
        for (int nt = 0; nt < 4; ++nt) {
            const int jj = nt * 16 + n;
            w2v[nt] = w2[jj];
            uv[nt]  = b1[jj] + sUP[jj] + sUP[64 + jj];
            bF[nt][0] = *(const bf16x8*)&sMt[jj * ROW + quad * 8];
            bF[nt][1] = *(const bf16x8*)&sMt[jj * ROW + 32 + quad * 8];
        }
        __syncthreads();                               // B3: sMt/sUP now dead -> overlays safe

        for (int mt = wid; mt < 13; mt += 4) {
            const bf16x8 a0 = *(const bf16x8*)&sK[(mt * 16 + n) * ROW + quad * 8];
            const bf16x8 a1 = *(const bf16x8*)&sK[(mt * 16 + n) * ROW + 32 + quad * 8];
            float s0 = 0.f, s1 = 0.f, s2 = 0.f, s3 = 0.f;
            #pragma unroll
            for (int nt = 0; nt < 4; ++nt) {
                f32x4 acc = { uv[nt], uv[nt], uv[nt], uv[nt] };
                acc = __builtin_amdgcn_mfma_f32_16x16x32_bf16(a0, bF[nt][0], acc, 0, 0, 0);
                acc = __builtin_amdgcn_mfma_f32_16x16x32_bf16(a1, bF[nt][1], acc, 0, 0, 0);
                s0 = fmaf(fmaxf(acc[0], 0.f), w2v[nt], s0);
                s1 = fmaf(fmaxf(acc[1], 0.f), w2v[nt], s1);
                s2 = fmaf(fmaxf(acc[2], 0.f), w2v[nt], s2);
                s3 = fmaf(fmaxf(acc[3], 0.f), w2v[nt], s3);
            }
            #pragma unroll
            for (int off = 1; off < 16; off <<= 1) {
                s0 += __shfl_xor(s0, off);
                s1 += __shfl_xor(s1, off);
                s2 += __shfl_xor(s2, off);
                s3 += __shfl_xor(s3, off);
            }
            if (n == 0) {
                const int base = mt * 16 + quad * 4;
                sWgt[base + 0] = s0;
                sWgt[base + 1] = s1;
                sWgt[base + 2] = s2;
                sWgt[base + 3] = s3;
            }
        }
    }
    __syncthreads();                                   // B4

    // ---- softmax over t ----
    {
        const float score = (tid < T) ? (sWgt[tid] + b2v) : -1e30f;
        float m = score;
        #pragma unroll
        for (int off = 32; off > 0; off >>= 1) m = fmaxf(m, __shfl_xor(m, off));
        if (lane == 0) sRed[wid] = m;
        __syncthreads();                               // B5
        const float gmax = fmaxf(fmaxf(sRed[0], sRed[1]), fmaxf(sRed[2], sRed[3]));
        const float p = (tid < T) ? __expf(score - gmax) : 0.f;
        float s = p;
        #pragma unroll
        for (int off = 32; off > 0; off >>= 1) s += __shfl_xor(s, off);
        if (lane == 0) sRed[4 + wid] = s;
        __syncthreads();                               // B6
        const float gsum = sRed[4] + sRed[5] + sRed[6] + sRed[7];
        if (tid < T) sWgt[tid] = p / gsum;
    }
    __syncthreads();                                   // B7

    // ---- interest[e] = sum_t w[t] * k[t][e]  (t<200 only, 4x50 chunks) ----
    {
        const int e = tid & 63, ch = tid >> 6;
        float a = 0.f;
        #pragma unroll 10
        for (int tt = 0; tt < 50; ++tt) {
            const int t = ch * 50 + tt;
            a = fmaf(sWgt[t], (float)sK[t * ROW + e], a);
        }
        sIP[tid] = a;
    }
    __syncthreads();                                   // B8
    if (tid < 64) sInt[tid] = sIP[tid] + sIP[64 + tid] + sIP[128 + tid] + sIP[192 + tid];
    __syncthreads();                                   // B9

    // ---- deep MLP: 64 -> 128 -> 64 -> 1 ----
    if (tid < 128) {
        float a = db1[tid];
        #pragma unroll 8
        for (int e = 0; e < 64; ++e) a = fmaf(sInt[e], dw1[e * 128 + tid], a);
        sD1[tid] = fmaxf(a, 0.f);
    }
    __syncthreads();                                   // B10
    if (tid < 64) {
        float a = db2[tid];
        #pragma unroll 8
        for (int i = 0; i < 128; ++i) a = fmaf(sD1[i], dw2[i * 64 + tid], a);
        sD2[tid] = fmaxf(a, 0.f);
    }
    __syncthreads();                                   // B11
    if (tid < 64) {
        float v = sD2[tid] * ow[tid];
        #pragma unroll
        for (int off = 32; off > 0; off >>= 1) v += __shfl_xor(v, off);
        if (tid == 0) out[b] = 1.f / (1.f + __expf(-(v + ob[0])));
    }
}

// ============ fallback: verified kernel (ws too small; fp32 path) ============
__global__ __launch_bounds__(BDIM, 3) void din_kernel(
    const int* __restrict__ query,
    const int* __restrict__ keys,
    const float* __restrict__ embf,
    const bf16_t* __restrict__ emb16,
    const int use16,
    const float* __restrict__ w1,
    const float* __restrict__ b1,
    const float* __restrict__ w2,
    const float* __restrict__ b2,
    const float* __restrict__ dw1,
    const float* __restrict__ db1,
    const float* __restrict__ dw2,
    const float* __restrict__ db2,
    const float* __restrict__ ow,
    const float* __restrict__ ob,
    float* __restrict__ out)
{
    __shared__ __align__(16) char sRaw[TPAD * ROW * 2];
    __shared__ __align__(16) bf16_t sMt[64 * ROW];
    __shared__ float sU[64];
    __shared__ float sUP[256];
    __shared__ float sW2f[64];
    __shared__ float sWgt[256];
    __shared__ float sQf[64];
    __shared__ __align__(16) char sQtmp[128];
    __shared__ float sRed[8];
    __shared__ float sInt[64];
    __shared__ float sD1[128];
    __shared__ float sD2[64];

    const int tid  = threadIdx.x;
    const int lane = tid & 63;
    const int wid  = tid >> 6;
    const int b    = blockIdx.x;
    const float b2v = b2[0];

    uint4 kr[8];
    if (tid < T) {
        const int ki = keys[b * T + tid];
        if (use16) {
            const uint4* kp = (const uint4*)(emb16 + (size_t)ki * E);
            #pragma unroll
            for (int c = 0; c < 8; ++c) kr[c] = kp[c];
        } else {
            const float4* kp = (const float4*)(embf + (size_t)ki * E);
            #pragma unroll
            for (int c = 0; c < 8; ++c) {
                const float4 x = kp[2 * c], y = kp[2 * c + 1];
                union { bf16_t h[8]; uint4 v; } u;
                u.h[0] = (bf16_t)x.x; u.h[1] = (bf16_t)x.y; u.h[2] = (bf16_t)x.z; u.h[3] = (bf16_t)x.w;
                u.h[4] = (bf16_t)y.x; u.h[5] = (bf16_t)y.y; u.h[6] = (bf16_t)y.z; u.h[7] = (bf16_t)y.w;
                kr[c] = u.v;
            }
        }
    } else {
        #pragma unroll
        for (int c = 0; c < 8; ++c) kr[c] = make_uint4(0u, 0u, 0u, 0u);
    }

    const int qi = query[b];
    if (tid < 8) {
        uint4 qv;
        if (use16) {
            qv = ((const uint4*)(emb16 + (size_t)qi * E))[tid];
        } else {
            const float4 x = ((const float4*)(embf + (size_t)qi * E))[2 * tid];
            const float4 y = ((const float4*)(embf + (size_t)qi * E))[2 * tid + 1];
            union { bf16_t h[8]; uint4 v; } u;
            u.h[0] = (bf16_t)x.x; u.h[1] = (bf16_t)x.y; u.h[2] = (bf16_t)x.z; u.h[3] = (bf16_t)x.w;
            u.h[4] = (bf16_t)y.x; u.h[5] = (bf16_t)y.y; u.h[6] = (bf16_t)y.z; u.h[7] = (bf16_t)y.w;
            qv = u.v;
        }
        ((uint4*)sQtmp)[tid] = qv;
    }
    if (tid < 64) sW2f[tid] = w2[tid];
    __syncthreads();
    if (tid < 64) sQf[tid] = (float)((const bf16_t*)sQtmp)[tid];
    __syncthreads();

    {
        float* sTmp = (float*)sRaw;
        const int j = tid & 63, ec = tid >> 6;
        float au = 0.f;
        #pragma unroll
        for (int eo = 0; eo < 16; ++eo) {
            const int e = ec * 16 + eo;
            const float w1a = w1[e * 64 + j];
            const float w1b = w1[(64 + e) * 64 + j];
            const float w1c = w1[(128 + e) * 64 + j];
            const float w1d = w1[(192 + e) * 64 + j];
            sTmp[e * 65 + j] = w1b - w1c + sQf[e] * w1d;
            au = fmaf(sQf[e], w1a + w1c, au);
        }
        sUP[tid] = au;
    }
    __syncthreads();
    {
        const float* sTmp = (const float*)sRaw;
        const int e = tid & 63, jc = tid >> 6;
        #pragma unroll
        for (int jo = 0; jo < 16; ++jo) {
            const int j = jc * 16 + jo;
            sMt[j * ROW + e] = (bf16_t)sTmp[e * 65 + j];
        }
    }
    if (tid < 64) sU[tid] = b1[tid] + sUP[tid] + sUP[64 + tid] + sUP[128 + tid] + sUP[192 + tid];
    __syncthreads();

    bf16_t* sK = (bf16_t*)sRaw;
    {
        uint4* dst = (uint4*)(sK + tid * ROW);
        #pragma unroll
        for (int c = 0; c < 8; ++c) dst[c] = kr[c];
    }
    __syncthreads();

    {
        const int n    = lane & 15;
        const int quad = lane >> 4;
        float w2v[4], uv[4];
        bf16x8 bF[4][2];
        #pragma unroll
        for (int nt = 0; nt < 4; ++nt) {
            w2v[nt] = sW2f[nt * 16 + n];
            uv[nt]  = sU[nt * 16 + n];
            bF[nt][0] = *(const bf16x8*)&sMt[(nt * 16 + n) * ROW + quad * 8];
            bF[nt][1] = *(const bf16x8*)&sMt[(nt * 16 + n) * ROW + 32 + quad * 8];
        }
        #pragma unroll
        for (int i = 0; i < 4; ++i) {
            const int mt = wid * 4 + i;
            const bf16x8 a0 = *(const bf16x8*)&sK[(mt * 16 + n) * ROW + quad * 8];
            const bf16x8 a1 = *(const bf16x8*)&sK[(mt * 16 + n) * ROW + 32 + quad * 8];
            float s0 = 0.f, s1 = 0.f, s2 = 0.f, s3 = 0.f;
            #pragma unroll
            for (int nt = 0; nt < 4; ++nt) {
                f32x4 acc = { uv[nt], uv[nt], uv[nt], uv[nt] };
                acc = __builtin_amdgcn_mfma_f32_16x16x32_bf16(a0, bF[nt][0], acc, 0, 0, 0);
                acc = __builtin_amdgcn_mfma_f32_16x16x32_bf16(a1, bF[nt][1], acc, 0, 0, 0);
                s0 = fmaf(fmaxf(acc[0], 0.f), w2v[nt], s0);
                s1 = fmaf(fmaxf(acc[1], 0.f), w2v[nt], s1);
                s2 = fmaf(fmaxf(acc[2], 0.f), w2v[nt], s2);
                s3 = fmaf(fmaxf(acc[3], 0.f), w2v[nt], s3);
            }
            #pragma unroll
            for (int off = 1; off < 16; off <<= 1) {
                s0 += __shfl_xor(s0, off);
                s1 += __shfl_xor(s1, off);
                s2 += __shfl_xor(s2, off);
                s3 += __shfl_xor(s3, off);
            }
            if (n == 0) {
                const int base = mt * 16 + quad * 4;
                sWgt[base + 0] = s0;
                sWgt[base + 1] = s1;
                sWgt[base + 2] = s2;
                sWgt[base + 3] = s3;
            }
        }
    }
    __syncthreads();

    {
        const float score = (tid < T) ? (sWgt[tid] + b2v) : -1e30f;
        float m = score;
        #pragma unroll
        for (int off = 32; off > 0; off >>= 1) m = fmaxf(m, __shfl_xor(m, off));
        if (lane == 0) sRed[wid] = m;
        __syncthreads();
        const float gmax = fmaxf(fmaxf(sRed[0], sRed[1]), fmaxf(sRed[2], sRed[3]));
        const float p = (tid < T) ? __expf(score - gmax) : 0.f;
        float s = p;
        #pragma unroll
        for (int off = 32; off > 0; off >>= 1) s += __shfl_xor(s, off);
        if (lane == 0) sRed[4 + wid] = s;
        __syncthreads();
        const float gsum = sRed[4] + sRed[5] + sRed[6] + sRed[7];
        sWgt[tid] = p / gsum;
    }
    __syncthreads();

    {
        const int e = tid & 63, ch = tid >> 6;
        float a = 0.f;
        #pragma unroll 8
        for (int tt = 0; tt < 64; ++tt) {
            const int t = ch * 64 + tt;
            a = fmaf(sWgt[t], (float)sK[t * ROW + e], a);
        }
        sUP[tid] = a;
    }
    __syncthreads();
    if (tid < 64) sInt[tid] = sUP[tid] + sUP[64 + tid] + sUP[128 + tid] + sUP[192 + tid];
    __syncthreads();

    if (tid < 128) {
        float a = db1[tid];
        #pragma unroll 8
        for (int e = 0; e < 64; ++e) a = fmaf(sInt[e], dw1[e * 128 + tid], a);
        sD1[tid] = fmaxf(a, 0.f);
    }
    __syncthreads();
    if (tid < 64) {
        float a = db2[tid];
        #pragma unroll 8
        for (int i = 0; i < 128; ++i) a = fmaf(sD1[i], dw2[i * 64 + tid], a);
        sD2[tid] = fmaxf(a, 0.f);
    }
    __syncthreads();
    if (tid < 64) {
        float v = sD2[tid] * ow[tid];
        #pragma unroll
        for (int off = 32; off > 0; off >>= 1) v += __shfl_xor(v, off);
        if (tid == 0) out[b] = 1.f / (1.f + __expf(-(v + ob[0])));
    }
}

extern "C" void kernel_launch(void* const* d_in, const int* in_sizes, int n_in,
                              void* d_out, int out_size, void* d_ws, size_t ws_size,
                              hipStream_t stream) {
    const int*   query = (const int*)d_in[0];
    const int*   keys  = (const int*)d_in[1];
    const float* embf  = (const float*)d_in[2];
    const float* w1    = (const float*)d_in[3];
    const float* b1    = (const float*)d_in[4];
    const float* w2    = (const float*)d_in[5];
    const float* b2    = (const float*)d_in[6];
    const float* dw1   = (const float*)d_in[7];
    const float* db1   = (const float*)d_in[8];
    const float* dw2   = (const float*)d_in[9];
    const float* db2   = (const float*)d_in[10];
    const float* ow    = (const float*)d_in[11];
    const float* ob    = (const float*)d_in[12];
    float* out = (float*)d_out;
    const int B        = in_sizes[0];
    const int embElems = in_sizes[2];                  // VOCAB * E
    const size_t WOFF  = 49152;                        // Ap 16K | Ctf 16K | Dtf 16K

    if (ws_size >= WOFF + (size_t)embElems * 2) {
        float*  Ap    = (float*)d_ws;
        float*  Ctf   = (float*)((char*)d_ws + 16384);
        float*  Dtf   = (float*)((char*)d_ws + 32768);
        bf16_t* emb16 = (bf16_t*)((char*)d_ws + WOFF);
        const int n8 = embElems / 8;
        pre_cvt<<<16 + (n8 + 255) / 256, 256, 0, stream>>>(embf, emb16, n8,
                                                           w1, Ap, Ctf, Dtf);
        din_fast<<<B, BDIM, 0, stream>>>(query, keys, emb16, Ap, Ctf, Dtf,
                                         b1, w2, b2, dw1, db1, dw2, db2, ow, ob, out);
    } else {
        din_kernel<<<B, BDIM, 0, stream>>>(query, keys, embf, (const bf16_t*)d_ws, 0,
                                           w1, b1, w2, b2, dw1, db1, dw2, db2, ow, ob, out);
    }
}

// Round 9
// 166.844 us; speedup vs baseline: 1.3753x; 1.0013x over previous
//
#include <hip/hip_runtime.h>

#define T 200
#define E 64
#define TPAD 256
#define ROW 72          // bf16 elems per padded LDS row (144 B, 16B-aligned)
#define BDIM 256
#define TP 208          // padded A-tile rows (13 m-tiles)

typedef __bf16 bf16_t;
typedef __bf16 bf16x8 __attribute__((ext_vector_type(8)));
typedef float f32x4 __attribute__((ext_vector_type(4)));

// ---- merged pre-pass: blocks 0..15 fold w1; blocks 16.. convert emb ----
__global__ __launch_bounds__(256) void pre_cvt(const float* __restrict__ embf,
                                               bf16_t* __restrict__ emb16, int n8,
                                               const float* __restrict__ w1,
                                               float* __restrict__ Ap,
                                               float* __restrict__ Ctf,
                                               float* __restrict__ Dtf) {
    const int bid = blockIdx.x;
    if (bid < 16) {
        const int idx = bid * 256 + threadIdx.x;      // 0..4095
        const int e = idx >> 6, j = idx & 63;
        const float a = w1[e * 64 + j];
        const float b = w1[(64 + e) * 64 + j];
        const float c = w1[(128 + e) * 64 + j];
        const float d = w1[(192 + e) * 64 + j];
        Ap[e * 64 + j]  = a + c;
        Ctf[j * 64 + e] = b - c;
        Dtf[j * 64 + e] = d;
        return;
    }
    const int i = (bid - 16) * 256 + threadIdx.x;
    if (i >= n8) return;
    const float4* s = (const float4*)embf + (size_t)i * 2;
    const float4 a = s[0], b = s[1];
    union { bf16_t h[8]; uint4 v; } u;
    u.h[0] = (bf16_t)a.x; u.h[1] = (bf16_t)a.y; u.h[2] = (bf16_t)a.z; u.h[3] = (bf16_t)a.w;
    u.h[4] = (bf16_t)b.x; u.h[5] = (bf16_t)b.y; u.h[6] = (bf16_t)b.z; u.h[7] = (bf16_t)b.w;
    ((uint4*)emb16)[i] = u.v;
}

// ===== fast kernel: 2 batches/block, software-pipelined gathers =====
// Batch A runs the proven R2 structure; batch B's gathers are issued inside
// GEMM(A) (drained at B4, hidden under MFMA+shuffles), staged into sK once
// interest(A) frees it. LDS layout unchanged: 39936 B -> 4 blocks/CU.
__global__ __launch_bounds__(256, 4) void din_fast(
    const int* __restrict__ query,
    const int* __restrict__ keys,
    const bf16_t* __restrict__ emb16,
    const float* __restrict__ Ap,
    const float* __restrict__ Ctf,
    const float* __restrict__ Dtf,
    const float* __restrict__ b1,
    const float* __restrict__ w2,
    const float* __restrict__ b2,
    const float* __restrict__ dw1,
    const float* __restrict__ db1,
    const float* __restrict__ dw2,
    const float* __restrict__ db2,
    const float* __restrict__ ow,
    const float* __restrict__ ob,
    float* __restrict__ out,
    const int nB)
{
    __shared__ __align__(16) char smem[39936];
    bf16_t* sK   = (bf16_t*)smem;                 // [0,29952)  208x72 bf16 A-tile
    bf16_t* sMt  = (bf16_t*)(smem + 29952);       // [29952,39168) 64x72 bf16 M^T
    float*  sUP  = (float*)(smem + 39168);        // u partials (128)
    float*  sQf  = (float*)(smem + 39680);        // q fp32 (64)
    // overlays inside sMt region (dead after bF-load barrier of each batch):
    float*  sWgt = (float*)(smem + 29952);        // 208 scores/weights
    float*  sRed = (float*)(smem + 30784);        // 8
    float*  sInt = (float*)(smem + 30816);        // 64
    float*  sD1  = (float*)(smem + 31072);        // 128
    float*  sD2  = (float*)(smem + 31584);        // 64
    float*  sIP  = (float*)(smem + 31840);        // 256 interest partials

    const int tid  = threadIdx.x;
    const int lane = tid & 63;
    const int wid  = tid >> 6;
    const int bA   = blockIdx.x * 2;
    const bool hasB = (bA + 1) < nB;
    const int bB   = hasB ? (bA + 1) : bA;
    const float b2v = b2[0];
    const int c8    = tid & 7;
    const int rbase = tid >> 3;                        // 0..31
    const int n    = lane & 15;
    const int quad = lane >> 4;

    // ================= batch A =================
    // ---- phase 0: issue gathers (A) + query (A) ----
    uint4 kr[7];
    #pragma unroll
    for (int i = 0; i < 7; ++i) {
        const int t = rbase + 32 * i;
        if (t < T) {
            const int ki = keys[bA * T + t];
            kr[i] = ((const uint4*)(emb16 + (size_t)ki * E))[c8];
        } else {
            kr[i] = make_uint4(0u, 0u, 0u, 0u);
        }
    }
    const int qiA = query[bA];
    if (tid < 64) sQf[tid] = (float)emb16[(size_t)qiA * E + tid];
    __syncthreads();                                   // B0

    // ---- u partials (A) + M^T (A) ----
    if (tid < 128) {
        const int j = tid & 63, ec = tid >> 6;
        float au = 0.f;
        #pragma unroll
        for (int eo = 0; eo < 32; ++eo) {
            const int e = ec * 32 + eo;
            au = fmaf(sQf[e], Ap[e * 64 + j], au);
        }
        sUP[tid] = au;
    }
    {
        const int j = tid & 63, h = tid >> 6;
        const float* cp = Ctf + j * 64 + h * 16;
        const float* dp = Dtf + j * 64 + h * 16;
        const float* qp = sQf + h * 16;
        bf16_t mo[16] __attribute__((aligned(16)));
        #pragma unroll
        for (int x = 0; x < 16; ++x)
            mo[x] = (bf16_t)fmaf(qp[x], dp[x], cp[x]);
        *(bf16x8*)&sMt[j * ROW + h * 16]     = *(bf16x8*)&mo[0];
        *(bf16x8*)&sMt[j * ROW + h * 16 + 8] = *(bf16x8*)&mo[8];
    }
    __syncthreads();                                   // B1

    // ---- stage k rows (A) into sK; kr regs retire ----
    #pragma unroll
    for (int i = 0; i < 7; ++i) {
        const int t = rbase + 32 * i;
        if (t < TP) *(uint4*)&sK[t * ROW + c8 * 8] = kr[i];
    }
    __syncthreads();                                   // B2

    // ---- GEMM (A) with batch-B prefetch hidden inside ----
    float w2v[4], uv[4];
    bf16x8 bF[4][2];
    float qpre = 0.f;
    {
        #pragma unroll
        for (int nt = 0; nt < 4; ++nt) {
            const int jj = nt * 16 + n;
            w2v[nt] = w2[jj];
            uv[nt]  = b1[jj] + sUP[jj] + sUP[64 + jj];
            bF[nt][0] = *(const bf16x8*)&sMt[jj * ROW + quad * 8];
            bF[nt][1] = *(const bf16x8*)&sMt[jj * ROW + 32 + quad * 8];
        }
        __syncthreads();                               // B3: overlays safe

        // prefetch batch B: gathers + query, drained at B4 (under GEMM)
        #pragma unroll
        for (int i = 0; i < 7; ++i) {
            const int t = rbase + 32 * i;
            if (t < T) {
                const int ki = keys[bB * T + t];
                kr[i] = ((const uint4*)(emb16 + (size_t)ki * E))[c8];
            } else {
                kr[i] = make_uint4(0u, 0u, 0u, 0u);
            }
        }
        if (tid < 64) qpre = (float)emb16[(size_t)query[bB] * E + tid];

        for (int mt = wid; mt < 13; mt += 4) {
            const bf16x8 a0 = *(const bf16x8*)&sK[(mt * 16 + n) * ROW + quad * 8];
            const bf16x8 a1 = *(const bf16x8*)&sK[(mt * 16 + n) * ROW + 32 + quad * 8];
            float s0 = 0.f, s1 = 0.f, s2 = 0.f, s3 = 0.f;
            #pragma unroll
            for (int nt = 0; nt < 4; ++nt) {
                f32x4 acc = { uv[nt], uv[nt], uv[nt], uv[nt] };
                acc = __builtin_amdgcn_mfma_f32_16x16x32_bf16(a0, bF[nt][0], acc, 0, 0, 0);
                acc = __builtin_amdgcn_mfma_f32_16x16x32_bf16(a1, bF[nt][1], acc, 0, 0, 0);
                s0 = fmaf(fmaxf(acc[0], 0.f), w2v[nt], s0);
                s1 = fmaf(fmaxf(acc[1], 0.f), w2v[nt], s1);
                s2 = fmaf(fmaxf(acc[2], 0.f), w2v[nt], s2);
                s3 = fmaf(fmaxf(acc[3], 0.f), w2v[nt], s3);
            }
            #pragma unroll
            for (int off = 1; off < 16; off <<= 1) {
                s0 += __shfl_xor(s0, off);
                s1 += __shfl_xor(s1, off);
                s2 += __shfl_xor(s2, off);
                s3 += __shfl_xor(s3, off);
            }
            if (n == 0) {
                const int base = mt * 16 + quad * 4;
                sWgt[base + 0] = s0;
                sWgt[base + 1] = s1;
                sWgt[base + 2] = s2;
                sWgt[base + 3] = s3;
            }
        }
    }
    __syncthreads();                                   // B4

    // ---- softmax (A) ----
    {
        const float score = (tid < T) ? (sWgt[tid] + b2v) : -1e30f;
        float m = score;
        #pragma unroll
        for (int off = 32; off > 0; off >>= 1) m = fmaxf(m, __shfl_xor(m, off));
        if (lane == 0) sRed[wid] = m;
        __syncthreads();                               // B5
        const float gmax = fmaxf(fmaxf(sRed[0], sRed[1]), fmaxf(sRed[2], sRed[3]));
        const float p = (tid < T) ? __expf(score - gmax) : 0.f;
        float s = p;
        #pragma unroll
        for (int off = 32; off > 0; off >>= 1) s += __shfl_xor(s, off);
        if (lane == 0) sRed[4 + wid] = s;
        __syncthreads();                               // B6
        const float gsum = sRed[4] + sRed[5] + sRed[6] + sRed[7];
        if (tid < T) sWgt[tid] = p / gsum;
    }
    __syncthreads();                                   // B7

    // ---- interest (A) ----
    {
        const int e = tid & 63, ch = tid >> 6;
        float a = 0.f;
        #pragma unroll 10
        for (int tt = 0; tt < 50; ++tt) {
            const int t = ch * 50 + tt;
            a = fmaf(sWgt[t], (float)sK[t * ROW + e], a);
        }
        sIP[tid] = a;
    }
    __syncthreads();                                   // B8: sK(A) dead

    // ---- stage batch-B rows into sK (loads long complete) + publish q(B) ----
    #pragma unroll
    for (int i = 0; i < 7; ++i) {
        const int t = rbase + 32 * i;
        if (t < TP) *(uint4*)&sK[t * ROW + c8 * 8] = kr[i];
    }
    if (tid < 64) {
        sQf[tid] = qpre;
        sInt[tid] = sIP[tid] + sIP[64 + tid] + sIP[128 + tid] + sIP[192 + tid];
    }
    __syncthreads();                                   // B9

    // ---- deep MLP (A) ----
    if (tid < 128) {
        float a = db1[tid];
        #pragma unroll 8
        for (int e = 0; e < 64; ++e) a = fmaf(sInt[e], dw1[e * 128 + tid], a);
        sD1[tid] = fmaxf(a, 0.f);
    }
    __syncthreads();                                   // B10
    if (tid < 64) {
        float a = db2[tid];
        #pragma unroll 8
        for (int i = 0; i < 128; ++i) a = fmaf(sD1[i], dw2[i * 64 + tid], a);
        sD2[tid] = fmaxf(a, 0.f);
    }
    __syncthreads();                                   // B11
    if (tid < 64) {
        float v = sD2[tid] * ow[tid];
        #pragma unroll
        for (int off = 32; off > 0; off >>= 1) v += __shfl_xor(v, off);
        if (tid == 0) out[bA] = 1.f / (1.f + __expf(-(v + ob[0])));
    }

    // ================= batch B =================
    if (hasB) {
        __syncthreads();                               // B12: sD2 read done -> sMt free

        // ---- u partials (B) + M^T (B) ----
        if (tid < 128) {
            const int j = tid & 63, ec = tid >> 6;
            float au = 0.f;
            #pragma unroll
            for (int eo = 0; eo < 32; ++eo) {
                const int e = ec * 32 + eo;
                au = fmaf(sQf[e], Ap[e * 64 + j], au);
            }
            sUP[tid] = au;
        }
        {
            const int j = tid & 63, h = tid >> 6;
            const float* cp = Ctf + j * 64 + h * 16;
            const float* dp = Dtf + j * 64 + h * 16;
            const float* qp = sQf + h * 16;
            bf16_t mo[16] __attribute__((aligned(16)));
            #pragma unroll
            for (int x = 0; x < 16; ++x)
                mo[x] = (bf16_t)fmaf(qp[x], dp[x], cp[x]);
            *(bf16x8*)&sMt[j * ROW + h * 16]     = *(bf16x8*)&mo[0];
            *(bf16x8*)&sMt[j * ROW + h * 16 + 8] = *(bf16x8*)&mo[8];
        }
        __syncthreads();                               // B13

        // ---- bF/uv (B) ----
        #pragma unroll
        for (int nt = 0; nt < 4; ++nt) {
            const int jj = nt * 16 + n;
            uv[nt]  = b1[jj] + sUP[jj] + sUP[64 + jj];
            bF[nt][0] = *(const bf16x8*)&sMt[jj * ROW + quad * 8];
            bF[nt][1] = *(const bf16x8*)&sMt[jj * ROW + 32 + quad * 8];
        }
        __syncthreads();                               // B14: overlays safe

        // ---- GEMM (B) ----
        for (int mt = wid; mt < 13; mt += 4) {
            const bf16x8 a0 = *(const bf16x8*)&sK[(mt * 16 + n) * ROW + quad * 8];
            const bf16x8 a1 = *(const bf16x8*)&sK[(mt * 16 + n) * ROW + 32 + quad * 8];
            float s0 = 0.f, s1 = 0.f, s2 = 0.f, s3 = 0.f;
            #pragma unroll
            for (int nt = 0; nt < 4; ++nt) {
                f32x4 acc = { uv[nt], uv[nt], uv[nt], uv[nt] };
                acc = __builtin_amdgcn_mfma_f32_16x16x32_bf16(a0, bF[nt][0], acc, 0, 0, 0);
                acc = __builtin_amdgcn_mfma_f32_16x16x32_bf16(a1, bF[nt][1], acc, 0, 0, 0);
                s0 = fmaf(fmaxf(acc[0], 0.f), w2v[nt], s0);
                s1 = fmaf(fmaxf(acc[1], 0.f), w2v[nt], s1);
                s2 = fmaf(fmaxf(acc[2], 0.f), w2v[nt], s2);
                s3 = fmaf(fmaxf(acc[3], 0.f), w2v[nt], s3);
            }
            #pragma unroll
            for (int off = 1; off < 16; off <<= 1) {
                s0 += __shfl_xor(s0, off);
                s1 += __shfl_xor(s1, off);
                s2 += __shfl_xor(s2, off);
                s3 += __shfl_xor(s3, off);
            }
            if (n == 0) {
                const int base = mt * 16 + quad * 4;
                sWgt[base + 0] = s0;
                sWgt[base + 1] = s1;
                sWgt[base + 2] = s2;
                sWgt[base + 3] = s3;
            }
        }
        __syncthreads();                               // B15

        // ---- softmax (B) ----
        {
            const float score = (tid < T) ? (sWgt[tid] + b2v) : -1e30f;
            float m = score;
            #pragma unroll
            for (int off = 32; off > 0; off >>= 1) m = fmaxf(m, __shfl_xor(m, off));
            if (lane == 0) sRed[wid] = m;
            __syncthreads();                           // B16
            const float gmax = fmaxf(fmaxf(sRed[0], sRed[1]), fmaxf(sRed[2], sRed[3]));
            const float p = (tid < T) ? __expf(score - gmax) : 0.f;
            float s = p;
            #pragma unroll
            for (int off = 32; off > 0; off >>= 1) s += __shfl_xor(s, off);
            if (lane == 0) sRed[4 + wid] = s;
            __syncthreads();                           // B17
            const float gsum = sRed[4] + sRed[5] + sRed[6] + sRed[7];
            if (tid < T) sWgt[tid] = p / gsum;
        }
        __syncthreads();                               // B18

        // ---- interest (B) ----
        {
            const int e = tid & 63, ch = tid >> 6;
            float a = 0.f;
            #pragma unroll 10
            for (int tt = 0; tt < 50; ++tt) {
                const int t = ch * 50 + tt;
                a = fmaf(sWgt[t], (float)sK[t * ROW + e], a);
            }
            sIP[tid] = a;
        }
        __syncthreads();                               // B19
        if (tid < 64) sInt[tid] = sIP[tid] + sIP[64 + tid] + sIP[128 + tid] + sIP[192 + tid];
        __syncthreads();                               // B20

        // ---- deep MLP (B) ----
        if (tid < 128) {
            float a = db1[tid];
            #pragma unroll 8
            for (int e = 0; e < 64; ++e) a = fmaf(sInt[e], dw1[e * 128 + tid], a);
            sD1[tid] = fmaxf(a, 0.f);
        }
        __syncthreads();                               // B21
        if (tid < 64) {
            float a = db2[tid];
            #pragma unroll 8
            for (int i = 0; i < 128; ++i) a = fmaf(sD1[i], dw2[i * 64 + tid], a);
            sD2[tid] = fmaxf(a, 0.f);
        }
        __syncthreads();                               // B22
        if (tid < 64) {
            float v = sD2[tid] * ow[tid];
            #pragma unroll
            for (int off = 32; off > 0; off >>= 1) v += __shfl_xor(v, off);
            if (tid == 0) out[bA + 1] = 1.f / (1.f + __expf(-(v + ob[0])));
        }
    }
}

// ============ fallback: verified kernel (ws too small; fp32 path) ============
__global__ __launch_bounds__(BDIM, 3) void din_kernel(
    const int* __restrict__ query,
    const int* __restrict__ keys,
    const float* __restrict__ embf,
    const bf16_t* __restrict__ emb16,
    const int use16,
    const float* __restrict__ w1,
    const float* __restrict__ b1,
    const float* __restrict__ w2,
    const float* __restrict__ b2,
    const float* __restrict__ dw1,
    const float* __restrict__ db1,
    const float* __restrict__ dw2,
    const float* __restrict__ db2,
    const float* __restrict__ ow,
    const float* __restrict__ ob,
    float* __restrict__ out)
{
    __shared__ __align__(16) char sRaw[TPAD * ROW * 2];
    __shared__ __align__(16) bf16_t sMt[64 * ROW];
    __shared__ float sU[64];
    __shared__ float sUP[256];
    __shared__ float sW2f[64];
    __shared__ float sWgt[256];
    __shared__ float sQf[64];
    __shared__ __align__(16) char sQtmp[128];
    __shared__ float sRed[8];
    __shared__ float sInt[64];
    __shared__ float sD1[128];
    __shared__ float sD2[64];

    const int tid  = threadIdx.x;
    const int lane = tid & 63;
    const int wid  = tid >> 6;
    const int b    = blockIdx.x;
    const float b2v = b2[0];

    uint4 kr[8];
    if (tid < T) {
        const int ki = keys[b * T + tid];
        if (use16) {
            const uint4* kp = (const uint4*)(emb16 + (size_t)ki * E);
            #pragma unroll
            for (int c = 0; c < 8; ++c) kr[c] = kp[c];
        } else {
            const float4* kp = (const float4*)(embf + (size_t)ki * E);
            #pragma unroll
            for (int c = 0; c < 8; ++c) {
                const float4 x = kp[2 * c], y = kp[2 * c + 1];
                union { bf16_t h[8]; uint4 v; } u;
                u.h[0] = (bf16_t)x.x; u.h[1] = (bf16_t)x.y; u.h[2] = (bf16_t)x.z; u.h[3] = (bf16_t)x.w;
                u.h[4] = (bf16_t)y.x; u.h[5] = (bf16_t)y.y; u.h[6] = (bf16_t)y.z; u.h[7] = (bf16_t)y.w;
                kr[c] = u.v;
            }
        }
    } else {
        #pragma unroll
        for (int c = 0; c < 8; ++c) kr[c] = make_uint4(0u, 0u, 0u, 0u);
    }

    const int qi = query[b];
    if (tid < 8) {
        uint4 qv;
        if (use16) {
            qv = ((const uint4*)(emb16 + (size_t)qi * E))[tid];
        } else {
            const float4 x = ((const float4*)(embf + (size_t)qi * E))[2 * tid];
            const float4 y = ((const float4*)(embf + (size_t)qi * E))[2 * tid + 1];
            union { bf16_t h[8]; uint4 v; } u;
            u.h[0] = (bf16_t)x.x; u.h[1] = (bf16_t)x.y; u.h[2] = (bf16_t)x.z; u.h[3] = (bf16_t)x.w;
            u.h[4] = (bf16_t)y.x; u.h[5] = (bf16_t)y.y; u.h[6] = (bf16_t)y.z; u.h[7] = (bf16_t)y.w;
            qv = u.v;
        }
        ((uint4*)sQtmp)[tid] = qv;
    }
    if (tid < 64) sW2f[tid] = w2[tid];
    __syncthreads();
    if (tid < 64) sQf[tid] = (float)((const bf16_t*)sQtmp)[tid];
    __syncthreads();

    {
        float* sTmp = (float*)sRaw;
        const int j = tid & 63, ec = tid >> 6;
        float au = 0.f;
        #pragma unroll
        for (int eo = 0; eo < 16; ++eo) {
            const int e = ec * 16 + eo;
            const float w1a = w1[e * 64 + j];
            const float w1b = w1[(64 + e) * 64 + j];
            const float w1c = w1[(128 + e) * 64 + j];
            const float w1d = w1[(192 + e) * 64 + j];
            sTmp[e * 65 + j] = w1b - w1c + sQf[e] * w1d;
            au = fmaf(sQf[e], w1a + w1c, au);
        }
        sUP[tid] = au;
    }
    __syncthreads();
    {
        const float* sTmp = (const float*)sRaw;
        const int e = tid & 63, jc = tid >> 6;
        #pragma unroll
        for (int jo = 0; jo < 16; ++jo) {
            const int j = jc * 16 + jo;
            sMt[j * ROW + e] = (bf16_t)sTmp[e * 65 + j];
        }
    }
    if (tid < 64) sU[tid] = b1[tid] + sUP[tid] + sUP[64 + tid] + sUP[128 + tid] + sUP[192 + tid];
    __syncthreads();

    bf16_t* sK = (bf16_t*)sRaw;
    {
        uint4* dst = (uint4*)(sK + tid * ROW);
        #pragma unroll
        for (int c = 0; c < 8; ++c) dst[c] = kr[c];
    }
    __syncthreads();

    {
        const int n    = lane & 15;
        const int quad = lane >> 4;
        float w2v[4], uv[4];
        bf16x8 bF[4][2];
        #pragma unroll
        for (int nt = 0; nt < 4; ++nt) {
            w2v[nt] = sW2f[nt * 16 + n];
            uv[nt]  = sU[nt * 16 + n];
            bF[nt][0] = *(const bf16x8*)&sMt[(nt * 16 + n) * ROW + quad * 8];
            bF[nt][1] = *(const bf16x8*)&sMt[(nt * 16 + n) * ROW + 32 + quad * 8];
        }
        #pragma unroll
        for (int i = 0; i < 4; ++i) {
            const int mt = wid * 4 + i;
            const bf16x8 a0 = *(const bf16x8*)&sK[(mt * 16 + n) * ROW + quad * 8];
            const bf16x8 a1 = *(const bf16x8*)&sK[(mt * 16 + n) * ROW + 32 + quad * 8];
            float s0 = 0.f, s1 = 0.f, s2 = 0.f, s3 = 0.f;
            #pragma unroll
            for (int nt = 0; nt < 4; ++nt) {
                f32x4 acc = { uv[nt], uv[nt], uv[nt], uv[nt] };
                acc = __builtin_amdgcn_mfma_f32_16x16x32_bf16(a0, bF[nt][0], acc, 0, 0, 0);
                acc = __builtin_amdgcn_mfma_f32_16x16x32_bf16(a1, bF[nt][1], acc, 0, 0, 0);
                s0 = fmaf(fmaxf(acc[0], 0.f), w2v[nt], s0);
                s1 = fmaf(fmaxf(acc[1], 0.f), w2v[nt], s1);
                s2 = fmaf(fmaxf(acc[2], 0.f), w2v[nt], s2);
                s3 = fmaf(fmaxf(acc[3], 0.f), w2v[nt], s3);
            }
            #pragma unroll
            for (int off = 1; off < 16; off <<= 1) {
                s0 += __shfl_xor(s0, off);
                s1 += __shfl_xor(s1, off);
                s2 += __shfl_xor(s2, off);
                s3 += __shfl_xor(s3, off);
            }
            if (n == 0) {
                const int base = mt * 16 + quad * 4;
                sWgt[base + 0] = s0;
                sWgt[base + 1] = s1;
                sWgt[base + 2] = s2;
                sWgt[base + 3] = s3;
            }
        }
    }
    __syncthreads();

    {
        const float score = (tid < T) ? (sWgt[tid] + b2v) : -1e30f;
        float m = score;
        #pragma unroll
        for (int off = 32; off > 0; off >>= 1) m = fmaxf(m, __shfl_xor(m, off));
        if (lane == 0) sRed[wid] = m;
        __syncthreads();
        const float gmax = fmaxf(fmaxf(sRed[0], sRed[1]), fmaxf(sRed[2], sRed[3]));
        const float p = (tid < T) ? __expf(score - gmax) : 0.f;
        float s = p;
        #pragma unroll
        for (int off = 32; off > 0; off >>= 1) s += __shfl_xor(s, off);
        if (lane == 0) sRed[4 + wid] = s;
        __syncthreads();
        const float gsum = sRed[4] + sRed[5] + sRed[6] + sRed[7];
        sWgt[tid] = p / gsum;
    }
    __syncthreads();

    {
        const int e = tid & 63, ch = tid >> 6;
        float a = 0.f;
        #pragma unroll 8
        for (int tt = 0; tt < 64; ++tt) {
            const int t = ch * 64 + tt;
            a = fmaf(sWgt[t], (float)sK[t * ROW + e], a);
        }
        sUP[tid] = a;
    }
    __syncthreads();
    if (tid < 64) sInt[tid] = sUP[tid] + sUP[64 + tid] + sUP[128 + tid] + sUP[192 + tid];
    __syncthreads();

    if (tid < 128) {
        float a = db1[tid];
        #pragma unroll 8
        for (int e = 0; e < 64; ++e) a = fmaf(sInt[e], dw1[e * 128 + tid], a);
        sD1[tid] = fmaxf(a, 0.f);
    }
    __syncthreads();
    if (tid < 64) {
        float a = db2[tid];
        #pragma unroll 8
        for (int i = 0; i < 128; ++i) a = fmaf(sD1[i], dw2[i * 64 + tid], a);
        sD2[tid] = fmaxf(a, 0.f);
    }
    __syncthreads();
    if (tid < 64) {
        float v = sD2[tid] * ow[tid];
        #pragma unroll
        for (int off = 32; off > 0; off >>= 1) v += __shfl_xor(v, off);
        if (tid == 0) out[b] = 1.f / (1.f + __expf(-(v + ob[0])));
    }
}

extern "C" void kernel_launch(void* const* d_in, const int* in_sizes, int n_in,
                              void* d_out, int out_size, void* d_ws, size_t ws_size,
                              hipStream_t stream) {
    const int*   query = (const int*)d_in[0];
    const int*   keys  = (const int*)d_in[1];
    const float* embf  = (const float*)d_in[2];
    const float* w1    = (const float*)d_in[3];
    const float* b1    = (const float*)d_in[4];
    const float* w2    = (const float*)d_in[5];
    const float* b2    = (const float*)d_in[6];
    const float* dw1   = (const float*)d_in[7];
    const float* db1   = (const float*)d_in[8];
    const float* dw2   = (const float*)d_in[9];
    const float* db2   = (const float*)d_in[10];
    const float* ow    = (const float*)d_in[11];
    const float* ob    = (const float*)d_in[12];
    float* out = (float*)d_out;
    const int B        = in_sizes[0];
    const int embElems = in_sizes[2];                  // VOCAB * E
    const size_t WOFF  = 49152;                        // Ap 16K | Ctf 16K | Dtf 16K

    if (ws_size >= WOFF + (size_t)embElems * 2) {
        float*  Ap    = (float*)d_ws;
        float*  Ctf   = (float*)((char*)d_ws + 16384);
        float*  Dtf   = (float*)((char*)d_ws + 32768);
        bf16_t* emb16 = (bf16_t*)((char*)d_ws + WOFF);
        const int n8 = embElems / 8;
        pre_cvt<<<16 + (n8 + 255) / 256, 256, 0, stream>>>(embf, emb16, n8,
                                                           w1, Ap, Ctf, Dtf);
        din_fast<<<(B + 1) / 2, BDIM, 0, stream>>>(query, keys, emb16, Ap, Ctf, Dtf,
                                                   b1, w2, b2, dw1, db1, dw2, db2,
                                                   ow, ob, out, B);
    } else {
        din_kernel<<<B, BDIM, 0, stream>>>(query, keys, embf, (const bf16_t*)d_ws, 0,
                                           w1, b1, w2, b2, dw1, db1, dw2, db2, ow, ob, out);
    }
}

// Round 10
// 145.822 us; speedup vs baseline: 1.5736x; 1.1442x over previous
//
#include <hip/hip_runtime.h>

#define T 200
#define E 64
#define TPAD 256
#define ROW 72
#define BDIM 256

typedef __bf16 bf16_t;
typedef __bf16 bf16x8 __attribute__((ext_vector_type(8)));
typedef float f32x4 __attribute__((ext_vector_type(4)));

// ---- merged pre-pass: blocks 0..15 fold w1; blocks 16.. convert emb ----
__global__ __launch_bounds__(256) void pre_cvt(const float* __restrict__ embf,
                                               bf16_t* __restrict__ emb16, int n8,
                                               const float* __restrict__ w1,
                                               float* __restrict__ Ap,
                                               float* __restrict__ Ctf,
                                               float* __restrict__ Dtf) {
    const int bid = blockIdx.x;
    if (bid < 16) {
        const int idx = bid * 256 + threadIdx.x;      // 0..4095
        const int e = idx >> 6, j = idx & 63;
        const float a = w1[e * 64 + j];
        const float b = w1[(64 + e) * 64 + j];
        const float c = w1[(128 + e) * 64 + j];
        const float d = w1[(192 + e) * 64 + j];
        Ap[e * 64 + j]  = a + c;
        Ctf[j * 64 + e] = b - c;
        Dtf[j * 64 + e] = d;
        return;
    }
    const int i = (bid - 16) * 256 + threadIdx.x;
    if (i >= n8) return;
    const float4* s = (const float4*)embf + (size_t)i * 2;
    const float4 a = s[0], b = s[1];
    union { bf16_t h[8]; uint4 v; } u;
    u.h[0] = (bf16_t)a.x; u.h[1] = (bf16_t)a.y; u.h[2] = (bf16_t)a.z; u.h[3] = (bf16_t)a.w;
    u.h[4] = (bf16_t)b.x; u.h[5] = (bf16_t)b.y; u.h[6] = (bf16_t)b.z; u.h[7] = (bf16_t)b.w;
    ((uint4*)emb16)[i] = u.v;
}

// ===== R10: one WAVE per batch, zero __syncthreads =====
// K lives in MFMA A-fragments in registers (26 x bf16x8 = 104 VGPR), loaded
// directly from emb16 (fragment row n, cols quad*8 is gather-compatible).
// M^T built per-lane in registers (R5 code). Scores/softmax/interest/MLP are
// wave-internal: shfl + 1.6 KB per-wave LDS scratch, ordered by
// s_waitcnt lgkmcnt(0) + sched_barrier(0) (rule #18), never __syncthreads.
__global__ __launch_bounds__(256, 2) void din_wave(
    const int* __restrict__ query,
    const int* __restrict__ keys,
    const bf16_t* __restrict__ emb16,
    const float* __restrict__ Ap,
    const float* __restrict__ Ctf,
    const float* __restrict__ Dtf,
    const float* __restrict__ b1,
    const float* __restrict__ w2,
    const float* __restrict__ b2,
    const float* __restrict__ dw1,
    const float* __restrict__ db1,
    const float* __restrict__ dw2,
    const float* __restrict__ db2,
    const float* __restrict__ ow,
    const float* __restrict__ ob,
    float* __restrict__ out,
    const int nB)
{
    __shared__ __align__(16) char smem[4 * 1664];
    const int tid  = threadIdx.x;
    const int wid  = tid >> 6;
    const int lane = tid & 63;
    const int n    = lane & 15;
    const int quad = lane >> 4;
    const int b    = blockIdx.x * 4 + wid;
    if (b >= nB) return;                               // wave-uniform; no barriers in kernel

    float* sWgt = (float*)(smem + wid * 1664);         // 208 f32 scores/weights
    float* sInt = (float*)(smem + wid * 1664 + 832);   // 64 f32 interest
    float* sD1  = (float*)(smem + wid * 1664 + 1088);  // 128 f32 mlp hidden

    // ---- q fragments (bf16, same rounding as before) ----
    const int qi = query[b];
    const bf16x8 q0 = *(const bf16x8*)(emb16 + (size_t)qi * E + quad * 8);
    const bf16x8 q1 = *(const bf16x8*)(emb16 + (size_t)qi * E + 32 + quad * 8);

    // ---- keys for this lane's GEMM rows: t = mt*16 + n (clamped to row 0) ----
    int kidx[13];
    #pragma unroll
    for (int mt = 0; mt < 13; ++mt) {
        const int t = mt * 16 + n;
        kidx[mt] = (t < T) ? keys[b * T + t] : 0;
    }
    // ---- gather A-fragments directly into registers ----
    bf16x8 a0[13], a1[13];
    #pragma unroll
    for (int mt = 0; mt < 13; ++mt) {
        const bf16_t* rp = emb16 + (size_t)kidx[mt] * E;
        a0[mt] = *(const bf16x8*)(rp + quad * 8);
        a1[mt] = *(const bf16x8*)(rp + 32 + quad * 8);
    }

    // ---- u[lane] = sum_e q[e] * Ap[e][lane]  (q re-read scalar, L1-hot) ----
    float u = 0.f;
    #pragma unroll
    for (int e = 0; e < 64; ++e)
        u = fmaf((float)emb16[(size_t)qi * E + e], Ap[e * 64 + lane], u);

    float uv[4], w2v[4];
    #pragma unroll
    for (int nt = 0; nt < 4; ++nt) {
        const int jj = nt * 16 + n;
        uv[nt]  = b1[jj] + __shfl(u, jj);
        w2v[nt] = w2[jj];
    }

    // ---- build B-fragments (M^T) per-lane in registers (R5 numerics) ----
    bf16x8 bF[4][2];
    #pragma unroll
    for (int nt = 0; nt < 4; ++nt) {
        const int jj = nt * 16 + n;
        const float* cb = Ctf + jj * 64;
        const float* db = Dtf + jj * 64;
        union { bf16_t h[8]; bf16x8 v; } u0, u1;
        #pragma unroll
        for (int x = 0; x < 8; ++x) {
            u0.h[x] = (bf16_t)fmaf((float)q0[x], db[quad * 8 + x],      cb[quad * 8 + x]);
            u1.h[x] = (bf16_t)fmaf((float)q1[x], db[32 + quad * 8 + x], cb[32 + quad * 8 + x]);
        }
        bF[nt][0] = u0.v;
        bF[nt][1] = u1.v;
    }

    // ---- score GEMM (104 MFMA) + 16-lane reduce -> wave-local LDS ----
    #pragma unroll
    for (int mt = 0; mt < 13; ++mt) {
        float s0 = 0.f, s1 = 0.f, s2 = 0.f, s3 = 0.f;
        #pragma unroll
        for (int nt = 0; nt < 4; ++nt) {
            f32x4 acc = { uv[nt], uv[nt], uv[nt], uv[nt] };
            acc = __builtin_amdgcn_mfma_f32_16x16x32_bf16(a0[mt], bF[nt][0], acc, 0, 0, 0);
            acc = __builtin_amdgcn_mfma_f32_16x16x32_bf16(a1[mt], bF[nt][1], acc, 0, 0, 0);
            s0 = fmaf(fmaxf(acc[0], 0.f), w2v[nt], s0);
            s1 = fmaf(fmaxf(acc[1], 0.f), w2v[nt], s1);
            s2 = fmaf(fmaxf(acc[2], 0.f), w2v[nt], s2);
            s3 = fmaf(fmaxf(acc[3], 0.f), w2v[nt], s3);
        }
        #pragma unroll
        for (int off = 1; off < 16; off <<= 1) {
            s0 += __shfl_xor(s0, off);
            s1 += __shfl_xor(s1, off);
            s2 += __shfl_xor(s2, off);
            s3 += __shfl_xor(s3, off);
        }
        if (n == 0) {
            const int base = mt * 16 + quad * 4;
            sWgt[base + 0] = s0;
            sWgt[base + 1] = s1;
            sWgt[base + 2] = s2;
            sWgt[base + 3] = s3;
        }
    }
    asm volatile("s_waitcnt lgkmcnt(0)" ::: "memory");
    __builtin_amdgcn_sched_barrier(0);

    // ---- wave softmax (R6 single-wave form), normalization folded ----
    {
        const float b2v = b2[0];
        const float x0 = sWgt[lane] + b2v;
        const float x1 = sWgt[64 + lane] + b2v;
        const float x2 = sWgt[128 + lane] + b2v;
        const float x3 = (lane < 8) ? (sWgt[192 + lane] + b2v) : -1e30f;
        float m = fmaxf(fmaxf(x0, x1), fmaxf(x2, x3));
        #pragma unroll
        for (int off = 32; off > 0; off >>= 1) m = fmaxf(m, __shfl_xor(m, off));
        const float p0 = __expf(x0 - m);
        const float p1 = __expf(x1 - m);
        const float p2 = __expf(x2 - m);
        const float p3 = (lane < 8) ? __expf(x3 - m) : 0.f;
        float s = ((p0 + p1) + (p2 + p3));
        #pragma unroll
        for (int off = 32; off > 0; off >>= 1) s += __shfl_xor(s, off);
        const float inv = 1.f / s;
        sWgt[lane]       = p0 * inv;
        sWgt[64 + lane]  = p1 * inv;
        sWgt[128 + lane] = p2 * inv;
        if (lane < 8) sWgt[192 + lane] = p3 * inv;
    }
    asm volatile("s_waitcnt lgkmcnt(0)" ::: "memory");
    __builtin_amdgcn_sched_barrier(0);

    // ---- interest from the SAME register fragments: partial over 13 rows,
    //      then 16-lane tree over n; lanes n==0 publish to sInt ----
    {
        float pa[8], pb[8];
        #pragma unroll
        for (int x = 0; x < 8; ++x) { pa[x] = 0.f; pb[x] = 0.f; }
        #pragma unroll
        for (int mt = 0; mt < 13; ++mt) {
            const int t = mt * 16 + n;
            const float wt = (t < T) ? sWgt[t] : 0.f;
            #pragma unroll
            for (int x = 0; x < 8; ++x) {
                pa[x] = fmaf(wt, (float)a0[mt][x], pa[x]);
                pb[x] = fmaf(wt, (float)a1[mt][x], pb[x]);
            }
        }
        #pragma unroll
        for (int x = 0; x < 8; ++x) {
            #pragma unroll
            for (int off = 1; off < 16; off <<= 1) {
                pa[x] += __shfl_xor(pa[x], off);
                pb[x] += __shfl_xor(pb[x], off);
            }
        }
        if (n == 0) {
            #pragma unroll
            for (int x = 0; x < 8; ++x) {
                sInt[quad * 8 + x]      = pa[x];
                sInt[32 + quad * 8 + x] = pb[x];
            }
        }
    }
    asm volatile("s_waitcnt lgkmcnt(0)" ::: "memory");
    __builtin_amdgcn_sched_barrier(0);

    // ---- deep MLP 64 -> 128 (2 outputs/lane) ----
    {
        float d1a = db1[lane], d1b = db1[64 + lane];
        #pragma unroll
        for (int e = 0; e < 64; ++e) {
            const float ie = sInt[e];
            d1a = fmaf(ie, dw1[e * 128 + lane], d1a);
            d1b = fmaf(ie, dw1[e * 128 + 64 + lane], d1b);
        }
        sD1[lane]      = fmaxf(d1a, 0.f);
        sD1[64 + lane] = fmaxf(d1b, 0.f);
    }
    asm volatile("s_waitcnt lgkmcnt(0)" ::: "memory");
    __builtin_amdgcn_sched_barrier(0);

    // ---- 128 -> 64 -> 1 ----
    {
        float o = db2[lane];
        #pragma unroll
        for (int i = 0; i < 128; ++i)
            o = fmaf(sD1[i], dw2[i * 64 + lane], o);
        float v = fmaxf(o, 0.f) * ow[lane];
        #pragma unroll
        for (int off = 32; off > 0; off >>= 1) v += __shfl_xor(v, off);
        if (lane == 0) out[b] = 1.f / (1.f + __expf(-(v + ob[0])));
    }
}

// ============ fallback: verified kernel (ws too small; fp32 path) ============
__global__ __launch_bounds__(BDIM, 3) void din_kernel(
    const int* __restrict__ query,
    const int* __restrict__ keys,
    const float* __restrict__ embf,
    const bf16_t* __restrict__ emb16,
    const int use16,
    const float* __restrict__ w1,
    const float* __restrict__ b1,
    const float* __restrict__ w2,
    const float* __restrict__ b2,
    const float* __restrict__ dw1,
    const float* __restrict__ db1,
    const float* __restrict__ dw2,
    const float* __restrict__ db2,
    const float* __restrict__ ow,
    const float* __restrict__ ob,
    float* __restrict__ out)
{
    __shared__ __align__(16) char sRaw[TPAD * ROW * 2];
    __shared__ __align__(16) bf16_t sMt[64 * ROW];
    __shared__ float sU[64];
    __shared__ float sUP[256];
    __shared__ float sW2f[64];
    __shared__ float sWgt[256];
    __shared__ float sQf[64];
    __shared__ __align__(16) char sQtmp[128];
    __shared__ float sRed[8];
    __shared__ float sInt[64];
    __shared__ float sD1[128];
    __shared__ float sD2[64];

    const int tid  = threadIdx.x;
    const int lane = tid & 63;
    const int wid  = tid >> 6;
    const int b    = blockIdx.x;
    const float b2v = b2[0];

    uint4 kr[8];
    if (tid < T) {
        const int ki = keys[b * T + tid];
        if (use16) {
            const uint4* kp = (const uint4*)(emb16 + (size_t)ki * E);
            #pragma unroll
            for (int c = 0; c < 8; ++c) kr[c] = kp[c];
        } else {
            const float4* kp = (const float4*)(embf + (size_t)ki * E);
            #pragma unroll
            for (int c = 0; c < 8; ++c) {
                const float4 x = kp[2 * c], y = kp[2 * c + 1];
                union { bf16_t h[8]; uint4 v; } u;
                u.h[0] = (bf16_t)x.x; u.h[1] = (bf16_t)x.y; u.h[2] = (bf16_t)x.z; u.h[3] = (bf16_t)x.w;
                u.h[4] = (bf16_t)y.x; u.h[5] = (bf16_t)y.y; u.h[6] = (bf16_t)y.z; u.h[7] = (bf16_t)y.w;
                kr[c] = u.v;
            }
        }
    } else {
        #pragma unroll
        for (int c = 0; c < 8; ++c) kr[c] = make_uint4(0u, 0u, 0u, 0u);
    }

    const int qi = query[b];
    if (tid < 8) {
        uint4 qv;
        if (use16) {
            qv = ((const uint4*)(emb16 + (size_t)qi * E))[tid];
        } else {
            const float4 x = ((const float4*)(embf + (size_t)qi * E))[2 * tid];
            const float4 y = ((const float4*)(embf + (size_t)qi * E))[2 * tid + 1];
            union { bf16_t h[8]; uint4 v; } u;
            u.h[0] = (bf16_t)x.x; u.h[1] = (bf16_t)x.y; u.h[2] = (bf16_t)x.z; u.h[3] = (bf16_t)x.w;
            u.h[4] = (bf16_t)y.x; u.h[5] = (bf16_t)y.y; u.h[6] = (bf16_t)y.z; u.h[7] = (bf16_t)y.w;
            qv = u.v;
        }
        ((uint4*)sQtmp)[tid] = qv;
    }
    if (tid < 64) sW2f[tid] = w2[tid];
    __syncthreads();
    if (tid < 64) sQf[tid] = (float)((const bf16_t*)sQtmp)[tid];
    __syncthreads();

    {
        float* sTmp = (float*)sRaw;
        const int j = tid & 63, ec = tid >> 6;
        float au = 0.f;
        #pragma unroll
        for (int eo = 0; eo < 16; ++eo) {
            const int e = ec * 16 + eo;
            const float w1a = w1[e * 64 + j];
            const float w1b = w1[(64 + e) * 64 + j];
            const float w1c = w1[(128 + e) * 64 + j];
            const float w1d = w1[(192 + e) * 64 + j];
            sTmp[e * 65 + j] = w1b - w1c + sQf[e] * w1d;
            au = fmaf(sQf[e], w1a + w1c, au);
        }
        sUP[tid] = au;
    }
    __syncthreads();
    {
        const float* sTmp = (const float*)sRaw;
        const int e = tid & 63, jc = tid >> 6;
        #pragma unroll
        for (int jo = 0; jo < 16; ++jo) {
            const int j = jc * 16 + jo;
            sMt[j * ROW + e] = (bf16_t)sTmp[e * 65 + j];
        }
    }
    if (tid < 64) sU[tid] = b1[tid] + sUP[tid] + sUP[64 + tid] + sUP[128 + tid] + sUP[192 + tid];
    __syncthreads();

    bf16_t* sK = (bf16_t*)sRaw;
    {
        uint4* dst = (uint4*)(sK + tid * ROW);
        #pragma unroll
        for (int c = 0; c < 8; ++c) dst[c] = kr[c];
    }
    __syncthreads();

    {
        const int n    = lane & 15;
        const int quad = lane >> 4;
        float w2v[4], uv[4];
        bf16x8 bF[4][2];
        #pragma unroll
        for (int nt = 0; nt < 4; ++nt) {
            w2v[nt] = sW2f[nt * 16 + n];
            uv[nt]  = sU[nt * 16 + n];
            bF[nt][0] = *(const bf16x8*)&sMt[(nt * 16 + n) * ROW + quad * 8];
            bF[nt][1] = *(const bf16x8*)&sMt[(nt * 16 + n) * ROW + 32 + quad * 8];
        }
        #pragma unroll
        for (int i = 0; i < 4; ++i) {
            const int mt = wid * 4 + i;
            const bf16x8 a0 = *(const bf16x8*)&sK[(mt * 16 + n) * ROW + quad * 8];
            const bf16x8 a1 = *(const bf16x8*)&sK[(mt * 16 + n) * ROW + 32 + quad * 8];
            float s0 = 0.f, s1 = 0.f, s2 = 0.f, s3 = 0.f;
            #pragma unroll
            for (int nt = 0; nt < 4; ++nt) {
                f32x4 acc = { uv[nt], uv[nt], uv[nt], uv[nt] };
                acc = __builtin_amdgcn_mfma_f32_16x16x32_bf16(a0, bF[nt][0], acc, 0, 0, 0);
                acc = __builtin_amdgcn_mfma_f32_16x16x32_bf16(a1, bF[nt][1], acc, 0, 0, 0);
                s0 = fmaf(fmaxf(acc[0], 0.f), w2v[nt], s0);
                s1 = fmaf(fmaxf(acc[1], 0.f), w2v[nt], s1);
                s2 = fmaf(fmaxf(acc[2], 0.f), w2v[nt], s2);
                s3 = fmaf(fmaxf(acc[3], 0.f), w2v[nt], s3);
            }
            #pragma unroll
            for (int off = 1; off < 16; off <<= 1) {
                s0 += __shfl_xor(s0, off);
                s1 += __shfl_xor(s1, off);
                s2 += __shfl_xor(s2, off);
                s3 += __shfl_xor(s3, off);
            }
            if (n == 0) {
                const int base = mt * 16 + quad * 4;
                sWgt[base + 0] = s0;
                sWgt[base + 1] = s1;
                sWgt[base + 2] = s2;
                sWgt[base + 3] = s3;
            }
        }
    }
    __syncthreads();

    {
        const float score = (tid < T) ? (sWgt[tid] + b2v) : -1e30f;
        float m = score;
        #pragma unroll
        for (int off = 32; off > 0; off >>= 1) m = fmaxf(m, __shfl_xor(m, off));
        if (lane == 0) sRed[wid] = m;
        __syncthreads();
        const float gmax = fmaxf(fmaxf(sRed[0], sRed[1]), fmaxf(sRed[2], sRed[3]));
        const float p = (tid < T) ? __expf(score - gmax) : 0.f;
        float s = p;
        #pragma unroll
        for (int off = 32; off > 0; off >>= 1) s += __shfl_xor(s, off);
        if (lane == 0) sRed[4 + wid] = s;
        __syncthreads();
        const float gsum = sRed[4] + sRed[5] + sRed[6] + sRed[7];
        sWgt[tid] = p / gsum;
    }
    __syncthreads();

    {
        const int e = tid & 63, ch = tid >> 6;
        float a = 0.f;
        #pragma unroll 8
        for (int tt = 0; tt < 64; ++tt) {
            const int t = ch * 64 + tt;
            a = fmaf(sWgt[t], (float)sK[t * ROW + e], a);
        }
        sUP[tid] = a;
    }
    __syncthreads();
    if (tid < 64) sInt[tid] = sUP[tid] + sUP[64 + tid] + sUP[128 + tid] + sUP[192 + tid];
    __syncthreads();

    if (tid < 128) {
        float a = db1[tid];
        #pragma unroll 8
        for (int e = 0; e < 64; ++e) a = fmaf(sInt[e], dw1[e * 128 + tid], a);
        sD1[tid] = fmaxf(a, 0.f);
    }
    __syncthreads();
    if (tid < 64) {
        float a = db2[tid];
        #pragma unroll 8
        for (int i = 0; i < 128; ++i) a = fmaf(sD1[i], dw2[i * 64 + tid], a);
        sD2[tid] = fmaxf(a, 0.f);
    }
    __syncthreads();
    if (tid < 64) {
        float v = sD2[tid] * ow[tid];
        #pragma unroll
        for (int off = 32; off > 0; off >>= 1) v += __shfl_xor(v, off);
        if (tid == 0) out[b] = 1.f / (1.f + __expf(-(v + ob[0])));
    }
}

extern "C" void kernel_launch(void* const* d_in, const int* in_sizes, int n_in,
                              void* d_out, int out_size, void* d_ws, size_t ws_size,
                              hipStream_t stream) {
    const int*   query = (const int*)d_in[0];
    const int*   keys  = (const int*)d_in[1];
    const float* embf  = (const float*)d_in[2];
    const float* w1    = (const float*)d_in[3];
    const float* b1    = (const float*)d_in[4];
    const float* w2    = (const float*)d_in[5];
    const float* b2    = (const float*)d_in[6];
    const float* dw1   = (const float*)d_in[7];
    const float* db1   = (const float*)d_in[8];
    const float* dw2   = (const float*)d_in[9];
    const float* db2   = (const float*)d_in[10];
    const float* ow    = (const float*)d_in[11];
    const float* ob    = (const float*)d_in[12];
    float* out = (float*)d_out;
    const int B        = in_sizes[0];
    const int embElems = in_sizes[2];                  // VOCAB * E
    const size_t WOFF  = 49152;                        // Ap 16K | Ctf 16K | Dtf 16K

    if (ws_size >= WOFF + (size_t)embElems * 2) {
        float*  Ap    = (float*)d_ws;
        float*  Ctf   = (float*)((char*)d_ws + 16384);
        float*  Dtf   = (float*)((char*)d_ws + 32768);
        bf16_t* emb16 = (bf16_t*)((char*)d_ws + WOFF);
        const int n8 = embElems / 8;
        pre_cvt<<<16 + (n8 + 255) / 256, 256, 0, stream>>>(embf, emb16, n8,
                                                           w1, Ap, Ctf, Dtf);
        din_wave<<<(B + 3) / 4, BDIM, 0, stream>>>(query, keys, emb16, Ap, Ctf, Dtf,
                                                   b1, w2, b2, dw1, db1, dw2, db2,
                                                   ow, ob, out, B);
    } else {
        din_kernel<<<B, BDIM, 0, stream>>>(query, keys, embf, (const bf16_t*)d_ws, 0,
                                           w1, b1, w2, b2, dw1, db1, dw2, db2, ow, ob, out);
    }
}